// Round 1
// baseline (376.106 us; speedup 1.0000x reference)
//
#include <hip/hip_runtime.h>
#include <hip/hip_bf16.h>

#define T_TOK 4096
#define SDIM  400
#define EDIM  300
#define HID   150
#define HPAD  160
#define NSPAN 40915
#define MAXW  10

// ---------------- generic fp32 tiled GEMM body: C[M x 150] = act(A[MxK] @ B[Kx150] + bias)
// optional fused layer-3: out[m] = dot(relu(row), w3) + b3
// Block: 256 threads. Tile: 64 rows x 150 cols. Per-thread: 8 rows x 5 cols.
__device__ __forceinline__ void gemm_body(
    const float* __restrict__ A, int lda,
    const float* __restrict__ B, int ldb,
    const float* __restrict__ bias, int relu,
    const float* __restrict__ w3, const float* __restrict__ b3,
    float* __restrict__ C, int ldc, int M, int K, int m0,
    float (*As)[64], float (*Bs)[160], float (*red)[33])
{
    const int tid = threadIdx.x;
    const int r8  = tid >> 5;   // 0..7 row group
    const int c32 = tid & 31;   // 0..31 col lane

    float acc[8][5];
#pragma unroll
    for (int i = 0; i < 8; i++)
#pragma unroll
        for (int j = 0; j < 5; j++) acc[i][j] = 0.f;

    const int mrow = tid >> 2;  // 0..63 staging row
    const int kq   = tid & 3;   // 0..3 staging k-quad
    const bool mok = (m0 + mrow) < M;
    const float* Arow = A + (size_t)(m0 + mrow) * lda;

    for (int k0 = 0; k0 < K; k0 += 16) {
        const int kmax = min(16, K - k0);
        __syncthreads();
        // stage A chunk transposed: As[k][m]
        {
            float4 v = make_float4(0.f, 0.f, 0.f, 0.f);
            if (mok && kq * 4 < kmax)
                v = *reinterpret_cast<const float4*>(Arow + k0 + kq * 4);
            As[kq * 4 + 0][mrow] = v.x;
            As[kq * 4 + 1][mrow] = v.y;
            As[kq * 4 + 2][mrow] = v.z;
            As[kq * 4 + 3][mrow] = v.w;
        }
        // stage B chunk: Bs[k][c]
#pragma unroll
        for (int it = 0; it < 10; ++it) {
            int idx = tid + it * 256;          // 16*160 = 2560 = 10*256
            int k = idx / 160, c = idx - k * 160;
            float bv = 0.f;
            if (k < kmax && c < HID) bv = B[(size_t)(k0 + k) * ldb + c];
            Bs[k][c] = bv;
        }
        __syncthreads();

        auto step = [&](int kk) {
            const float4 a0 = *reinterpret_cast<const float4*>(&As[kk][r8 * 8]);
            const float4 a1 = *reinterpret_cast<const float4*>(&As[kk][r8 * 8 + 4]);
            float b[5];
#pragma unroll
            for (int j = 0; j < 5; j++) b[j] = Bs[kk][c32 + 32 * j];
            const float a[8] = {a0.x, a0.y, a0.z, a0.w, a1.x, a1.y, a1.z, a1.w};
#pragma unroll
            for (int i = 0; i < 8; i++)
#pragma unroll
                for (int j = 0; j < 5; j++)
                    acc[i][j] = fmaf(a[i], b[j], acc[i][j]);
        };
        if (kmax == 16) {
#pragma unroll
            for (int kk = 0; kk < 16; ++kk) step(kk);
        } else {
            for (int kk = 0; kk < kmax; ++kk) step(kk);
        }
    }

    float bv[5];
#pragma unroll
    for (int j = 0; j < 5; j++) {
        int c = c32 + 32 * j;
        bv[j] = (bias != nullptr && c < HID) ? bias[c] : 0.f;
    }

    if (w3 == nullptr) {
#pragma unroll
        for (int i = 0; i < 8; i++) {
            int gm = m0 + r8 * 8 + i;
            if (gm < M) {
#pragma unroll
                for (int j = 0; j < 5; j++) {
                    int c = c32 + 32 * j;
                    if (c < HID) {
                        float v = acc[i][j] + bv[j];
                        if (relu) v = fmaxf(v, 0.f);
                        C[(size_t)gm * ldc + c] = v;
                    }
                }
            }
        }
    } else {
        float w3v[5];
#pragma unroll
        for (int j = 0; j < 5; j++) {
            int c = c32 + 32 * j;
            w3v[j] = (c < HID) ? w3[c] : 0.f;
        }
#pragma unroll
        for (int i = 0; i < 8; i++) {
            float p = 0.f;
#pragma unroll
            for (int j = 0; j < 5; j++) {
                float v = fmaxf(acc[i][j] + bv[j], 0.f);   // relu before layer-3
                p = fmaf(v, w3v[j], p);
            }
            red[r8 * 8 + i][c32] = p;
        }
        __syncthreads();
        if (tid < 64) {
            float s = 0.f;
#pragma unroll
            for (int c = 0; c < 32; c++) s += red[tid][c];
            int gm = m0 + tid;
            if (gm < M) C[gm] = s + b3[0];
        }
    }
}

__global__ __launch_bounds__(256) void k_gemm(
    const float* __restrict__ A, int lda,
    const float* __restrict__ B, int ldb,
    const float* __restrict__ bias, int relu,
    const float* __restrict__ w3, const float* __restrict__ b3,
    float* __restrict__ C, int ldc, int M, int K)
{
    __shared__ float As[16][64];
    __shared__ float Bs[16][160];
    __shared__ float red[64][33];
    gemm_body(A, lda, B, ldb, bias, relu, w3, b3, C, ldc, M, K,
              blockIdx.x * 64, As, Bs, red);
}

// fused: H1a = relu(states@aW1+ab1); Abuf = states@sW1[0:400]; Bbuf = states@sW1[400:800]
__global__ __launch_bounds__(256) void k_states3(
    const float* __restrict__ states,
    const float* __restrict__ aW1, const float* __restrict__ ab1,
    const float* __restrict__ sW1,
    float* __restrict__ H1a, float* __restrict__ Abuf, float* __restrict__ Bbuf)
{
    __shared__ float As[16][64];
    __shared__ float Bs[16][160];
    __shared__ float red[64][33];
    const float* Bm; const float* bias = nullptr; float* C; int relu = 0;
    if (blockIdx.y == 0)      { Bm = aW1;              bias = ab1; C = H1a;  relu = 1; }
    else if (blockIdx.y == 1) { Bm = sW1;                          C = Abuf; }
    else                      { Bm = sW1 + 400 * HID;              C = Bbuf; }
    gemm_body(states, SDIM, Bm, HID, bias, relu, nullptr, nullptr,
              C, HPAD, T_TOK, SDIM, blockIdx.x * 64, As, Bs, red);
}

// scores[t] = dot(H2a[t], aW3) + ab3 ; one wave per token
__global__ __launch_bounds__(256) void k_scores(
    const float* __restrict__ H2a, const float* __restrict__ aW3,
    const float* __restrict__ ab3, float* __restrict__ scores)
{
    int wid  = (blockIdx.x * 256 + threadIdx.x) >> 6;
    int lane = threadIdx.x & 63;
    if (wid >= T_TOK) return;
    const float* row = H2a + (size_t)wid * HPAD;
    float s = 0.f;
    for (int d = lane; d < HID; d += 64) s = fmaf(row[d], aW3[d], s);
#pragma unroll
    for (int off = 32; off; off >>= 1) s += __shfl_down(s, off);
    if (lane == 0) scores[wid] = s + ab3[0];
}

// wc[n-1][c] = sb1[c] + sum_j width_table[dtoi(n)][j] * sW1[1100+j][c]
__global__ __launch_bounds__(192) void k_wconst(
    const float* __restrict__ wt, const float* __restrict__ sW1,
    const float* __restrict__ sb1, float* __restrict__ wc)
{
    int n = blockIdx.x + 1;
    int c = threadIdx.x;
    if (c >= HID) return;
    const int dt[11] = {0, 1, 2, 3, 4, 4, 4, 4, 5, 5, 5};
    const float* w = wt + dt[n] * 20;
    float s = sb1[c];
#pragma unroll
    for (int j = 0; j < 20; j++) s = fmaf(w[j], sW1[(1100 + j) * HID + c], s);
    wc[(n - 1) * HPAD + c] = s;
}

// one wave per span: softmax over n scores, h1 = relu(A[s]+B[e]+sum a_i E[s+i]+wc[n])
__global__ __launch_bounds__(256) void k_spans(
    const float* __restrict__ scores, const float* __restrict__ Abuf,
    const float* __restrict__ Bbuf, const float* __restrict__ Ebuf,
    const float* __restrict__ wc, float* __restrict__ h1sp)
{
    int span = (blockIdx.x * 256 + threadIdx.x) >> 6;
    int lane = threadIdx.x & 63;
    if (span >= NSPAN) return;

    int n = 1, base = 0;
#pragma unroll
    for (int i = 1; i <= MAXW; i++) {
        int w = T_TOK - i + 1;
        if (span < base + w) { n = i; break; }
        base += w;
    }
    const int start = span - base;
    const int end   = start + n - 1;

    float sc[MAXW];
#pragma unroll
    for (int i = 0; i < MAXW; i++)
        sc[i] = (i < n) ? scores[start + i] : -1e30f;
    float mx = sc[0];
#pragma unroll
    for (int i = 1; i < MAXW; i++) mx = fmaxf(mx, sc[i]);
    float ssum = 0.f;
#pragma unroll
    for (int i = 0; i < MAXW; i++) { sc[i] = __expf(sc[i] - mx); ssum += sc[i]; }
    const float inv = 1.f / ssum;
#pragma unroll
    for (int i = 0; i < MAXW; i++) sc[i] *= inv;

    const float* Ar  = Abuf + (size_t)start * HPAD;
    const float* Br  = Bbuf + (size_t)end * HPAD;
    const float* wcr = wc + (n - 1) * HPAD;
    float* out = h1sp + (size_t)span * HPAD;
#pragma unroll
    for (int slot = 0; slot < 3; ++slot) {
        int d = lane + slot * 64;
        if (d < HID) {
            float v = Ar[d] + Br[d] + wcr[d];
#pragma unroll
            for (int i = 0; i < MAXW; i++) {
                if (i >= n) break;
                v = fmaf(sc[i], Ebuf[(size_t)(start + i) * HPAD + d], v);
            }
            out[d] = fmaxf(v, 0.f);
        }
    }
}

extern "C" void kernel_launch(void* const* d_in, const int* in_sizes, int n_in,
                              void* d_out, int out_size, void* d_ws, size_t ws_size,
                              hipStream_t stream) {
    const float* embeds = (const float*)d_in[0];
    const float* states = (const float*)d_in[1];
    const float* aW1 = (const float*)d_in[2];
    const float* ab1 = (const float*)d_in[3];
    const float* aW2 = (const float*)d_in[4];
    const float* ab2 = (const float*)d_in[5];
    const float* aW3 = (const float*)d_in[6];
    const float* ab3 = (const float*)d_in[7];
    const float* wt  = (const float*)d_in[8];
    const float* sW1 = (const float*)d_in[9];
    const float* sb1 = (const float*)d_in[10];
    const float* sW2 = (const float*)d_in[11];
    const float* sb2 = (const float*)d_in[12];
    const float* sW3 = (const float*)d_in[13];
    const float* sb3 = (const float*)d_in[14];
    float* out = (float*)d_out;

    float* ws = (float*)d_ws;
    const size_t TP = (size_t)T_TOK * HPAD;      // 655360
    float* H1a    = ws;
    float* H2a    = H1a + TP;
    float* scores = H2a + TP;
    float* Abuf   = scores + T_TOK;
    float* Bbuf   = Abuf + TP;
    float* Ebuf   = Bbuf + TP;
    float* wcbuf  = Ebuf + TP;
    float* h1sp   = wcbuf + MAXW * HPAD;

    // attn layer1 + span-state projections (share states input)
    k_states3<<<dim3(T_TOK / 64, 3), 256, 0, stream>>>(states, aW1, ab1, sW1,
                                                       H1a, Abuf, Bbuf);
    // attn layer2
    k_gemm<<<T_TOK / 64, 256, 0, stream>>>(H1a, HPAD, aW2, HID, ab2, 1,
                                           nullptr, nullptr, H2a, HPAD, T_TOK, HID);
    // attn layer3 -> scores
    k_scores<<<T_TOK / 4, 256, 0, stream>>>(H2a, aW3, ab3, scores);
    // embeds projection E = embeds @ sW1[800:1100]
    k_gemm<<<T_TOK / 64, 256, 0, stream>>>(embeds, EDIM, sW1 + 800 * HID, HID,
                                           nullptr, 0, nullptr, nullptr,
                                           Ebuf, HPAD, T_TOK, EDIM);
    // width constants (includes sb1)
    k_wconst<<<MAXW, 192, 0, stream>>>(wt, sW1, sb1, wcbuf);
    // per-span softmax pooling + layer1 combine
    {
        int nblk = (NSPAN * 64 + 255) / 256;
        k_spans<<<nblk, 256, 0, stream>>>(scores, Abuf, Bbuf, Ebuf, wcbuf, h1sp);
    }
    // sm layer2 + fused layer3 -> out
    k_gemm<<<(NSPAN + 63) / 64, 256, 0, stream>>>(h1sp, HPAD, sW2, HID, sb2, 1,
                                                  sW3, sb3, out, 0, NSPAN, HID);
}

// Round 2
// 288.938 us; speedup vs baseline: 1.3017x; 1.3017x over previous
//
#include <hip/hip_runtime.h>
#include <hip/hip_bf16.h>

#define T_TOK 4096
#define SDIM  400
#define EDIM  300
#define HID   150
#define HPAD  160
#define NSPAN 40915
#define MAXW  10

// ---------------- fp32 tiled GEMM body: C[M x 150] = act(A[MxK] @ B[Kx150] + bias)
// optional fused layer-3: out[m] = dot(relu(row), w3) + b3
// Block: 256 threads. Tile: MT rows x 150 cols. Per-thread: MT/8 rows x 5 cols.
template <int MT>
__device__ __forceinline__ void gemm_body(
    const float* __restrict__ A, int lda,
    const float* __restrict__ B, int ldb,
    const float* __restrict__ bias, int relu,
    const float* __restrict__ w3, const float* __restrict__ b3,
    float* __restrict__ C, int ldc, int M, int K, int m0,
    float (*As)[MT], float (*Bs)[160], float (*red)[33])
{
    constexpr int R = MT / 8;
    const int tid = threadIdx.x;
    const int r8  = tid >> 5;   // 0..7 row group
    const int c32 = tid & 31;   // 0..31 col lane

    float acc[R][5];
#pragma unroll
    for (int i = 0; i < R; i++)
#pragma unroll
        for (int j = 0; j < 5; j++) acc[i][j] = 0.f;

    const int mrow = tid >> 2;            // staging row (valid if < MT)
    const int kq   = tid & 3;             // staging k-quad
    const bool stage_a = tid < MT * 4;
    const bool mok = stage_a && (m0 + mrow) < M;
    const float* Arow = A + (size_t)(m0 + mrow) * lda;

    for (int k0 = 0; k0 < K; k0 += 16) {
        const int kmax = min(16, K - k0);
        __syncthreads();
        // stage A chunk transposed: As[k][m]
        if (stage_a) {
            float4 v = make_float4(0.f, 0.f, 0.f, 0.f);
            if (mok && kq * 4 < kmax)
                v = *reinterpret_cast<const float4*>(Arow + k0 + kq * 4);
            As[kq * 4 + 0][mrow] = v.x;
            As[kq * 4 + 1][mrow] = v.y;
            As[kq * 4 + 2][mrow] = v.z;
            As[kq * 4 + 3][mrow] = v.w;
        }
        // stage B chunk: Bs[k][c]
#pragma unroll
        for (int it = 0; it < 10; ++it) {
            int idx = tid + it * 256;          // 16*160 = 2560 = 10*256
            int k = idx / 160, c = idx - k * 160;
            float bv = 0.f;
            if (k < kmax && c < HID) bv = B[(size_t)(k0 + k) * ldb + c];
            Bs[k][c] = bv;
        }
        __syncthreads();

        auto step = [&](int kk) {
            float a[R];
#pragma unroll
            for (int i = 0; i < R; i++) a[i] = As[kk][r8 * R + i];
            float b[5];
#pragma unroll
            for (int j = 0; j < 5; j++) b[j] = Bs[kk][c32 + 32 * j];
#pragma unroll
            for (int i = 0; i < R; i++)
#pragma unroll
                for (int j = 0; j < 5; j++)
                    acc[i][j] = fmaf(a[i], b[j], acc[i][j]);
        };
        if (kmax == 16) {
#pragma unroll
            for (int kk = 0; kk < 16; ++kk) step(kk);
        } else {
            for (int kk = 0; kk < kmax; ++kk) step(kk);
        }
    }

    float bv[5];
#pragma unroll
    for (int j = 0; j < 5; j++) {
        int c = c32 + 32 * j;
        bv[j] = (bias != nullptr && c < HID) ? bias[c] : 0.f;
    }

    if (w3 == nullptr) {
#pragma unroll
        for (int i = 0; i < R; i++) {
            int gm = m0 + r8 * R + i;
            if (gm < M) {
#pragma unroll
                for (int j = 0; j < 5; j++) {
                    int c = c32 + 32 * j;
                    if (c < HID) {
                        float v = acc[i][j] + bv[j];
                        if (relu) v = fmaxf(v, 0.f);
                        C[(size_t)gm * ldc + c] = v;
                    }
                }
            }
        }
    } else {
        float w3v[5];
#pragma unroll
        for (int j = 0; j < 5; j++) {
            int c = c32 + 32 * j;
            w3v[j] = (c < HID) ? w3[c] : 0.f;
        }
#pragma unroll
        for (int i = 0; i < R; i++) {
            float p = 0.f;
#pragma unroll
            for (int j = 0; j < 5; j++) {
                float v = fmaxf(acc[i][j] + bv[j], 0.f);   // relu before layer-3
                p = fmaf(v, w3v[j], p);
            }
            red[r8 * R + i][c32] = p;
        }
        __syncthreads();
        if (tid < MT) {
            float s = 0.f;
#pragma unroll
            for (int c = 0; c < 32; c++) s += red[tid][c];
            int gm = m0 + tid;
            if (gm < M) C[gm] = s + b3[0];
        }
    }
}

// fused per-token projections: y=0 H1a, y=1 A, y=2 B, y=3 E, y=4 wconst
__global__ __launch_bounds__(256) void k_proj(
    const float* __restrict__ states, const float* __restrict__ embeds,
    const float* __restrict__ aW1, const float* __restrict__ ab1,
    const float* __restrict__ sW1, const float* __restrict__ wt,
    const float* __restrict__ sb1,
    float* __restrict__ H1a, float* __restrict__ Abuf,
    float* __restrict__ Bbuf, float* __restrict__ Ebuf,
    float* __restrict__ wcbuf)
{
    if (blockIdx.y == 4) {
        // width constants: wc[n-1][c] = sb1[c] + sum_j wt[dtoi(n)][j]*sW1[1100+j][c]
        if (blockIdx.x < MAXW) {
            int n = blockIdx.x + 1;
            int c = threadIdx.x;
            if (c < HID) {
                const int dt[11] = {0, 1, 2, 3, 4, 4, 4, 4, 5, 5, 5};
                const float* w = wt + dt[n] * 20;
                float s = sb1[c];
#pragma unroll
                for (int j = 0; j < 20; j++)
                    s = fmaf(w[j], sW1[(1100 + j) * HID + c], s);
                wcbuf[(n - 1) * HPAD + c] = s;
            }
        }
        return;
    }
    __shared__ float As[16][16];
    __shared__ float Bs[16][160];
    const float* Am; int lda, K; const float* Bm;
    const float* bias = nullptr; int relu = 0; float* C;
    switch (blockIdx.y) {
        case 0: Am = states; lda = SDIM; K = SDIM; Bm = aW1;            bias = ab1; relu = 1; C = H1a;  break;
        case 1: Am = states; lda = SDIM; K = SDIM; Bm = sW1;                                  C = Abuf; break;
        case 2: Am = states; lda = SDIM; K = SDIM; Bm = sW1 + 400*HID;                        C = Bbuf; break;
        default:Am = embeds; lda = EDIM; K = EDIM; Bm = sW1 + 800*HID;                        C = Ebuf; break;
    }
    gemm_body<16>(Am, lda, Bm, HID, bias, relu, nullptr, nullptr,
                  C, HPAD, T_TOK, K, blockIdx.x * 16, As, Bs, nullptr);
}

// attn layer2 + fused layer3 -> scores
__global__ __launch_bounds__(256) void k_attn2(
    const float* __restrict__ H1a, const float* __restrict__ aW2,
    const float* __restrict__ ab2, const float* __restrict__ aW3,
    const float* __restrict__ ab3, float* __restrict__ scores)
{
    __shared__ float As[16][16];
    __shared__ float Bs[16][160];
    __shared__ float red[16][33];
    gemm_body<16>(H1a, HPAD, aW2, HID, ab2, 1, aW3, ab3,
                  scores, 0, T_TOK, HID, blockIdx.x * 16, As, Bs, red);
}

// one wave per span: softmax over n scores, h1 = relu(A[s]+B[e]+sum a_i E[s+i]+wc[n])
__global__ __launch_bounds__(256) void k_spans(
    const float* __restrict__ scores, const float* __restrict__ Abuf,
    const float* __restrict__ Bbuf, const float* __restrict__ Ebuf,
    const float* __restrict__ wc, float* __restrict__ h1sp)
{
    int span = (blockIdx.x * 256 + threadIdx.x) >> 6;
    int lane = threadIdx.x & 63;
    if (span >= NSPAN) return;

    int n = 1, base = 0;
#pragma unroll
    for (int i = 1; i <= MAXW; i++) {
        int w = T_TOK - i + 1;
        if (span < base + w) { n = i; break; }
        base += w;
    }
    const int start = span - base;
    const int end   = start + n - 1;

    float sc[MAXW];
#pragma unroll
    for (int i = 0; i < MAXW; i++)
        sc[i] = (i < n) ? scores[start + i] : -1e30f;
    float mx = sc[0];
#pragma unroll
    for (int i = 1; i < MAXW; i++) mx = fmaxf(mx, sc[i]);
    float ssum = 0.f;
#pragma unroll
    for (int i = 0; i < MAXW; i++) { sc[i] = __expf(sc[i] - mx); ssum += sc[i]; }
    const float inv = 1.f / ssum;
#pragma unroll
    for (int i = 0; i < MAXW; i++) sc[i] *= inv;

    const float* Ar  = Abuf + (size_t)start * HPAD;
    const float* Br  = Bbuf + (size_t)end * HPAD;
    const float* wcr = wc + (n - 1) * HPAD;
    float* out = h1sp + (size_t)span * HPAD;
#pragma unroll
    for (int slot = 0; slot < 3; ++slot) {
        int d = lane + slot * 64;
        if (d < HID) {
            float v = Ar[d] + Br[d] + wcr[d];
#pragma unroll
            for (int i = 0; i < MAXW; i++) {
                if (i >= n) break;
                v = fmaf(sc[i], Ebuf[(size_t)(start + i) * HPAD + d], v);
            }
            out[d] = fmaxf(v, 0.f);
        }
    }
}

// sm layer2 + fused layer3 -> out
__global__ __launch_bounds__(256) void k_final(
    const float* __restrict__ h1sp, const float* __restrict__ sW2,
    const float* __restrict__ sb2, const float* __restrict__ sW3,
    const float* __restrict__ sb3, float* __restrict__ out)
{
    __shared__ float As[16][32];
    __shared__ float Bs[16][160];
    __shared__ float red[32][33];
    gemm_body<32>(h1sp, HPAD, sW2, HID, sb2, 1, sW3, sb3,
                  out, 0, NSPAN, HID, blockIdx.x * 32, As, Bs, red);
}

extern "C" void kernel_launch(void* const* d_in, const int* in_sizes, int n_in,
                              void* d_out, int out_size, void* d_ws, size_t ws_size,
                              hipStream_t stream) {
    const float* embeds = (const float*)d_in[0];
    const float* states = (const float*)d_in[1];
    const float* aW1 = (const float*)d_in[2];
    const float* ab1 = (const float*)d_in[3];
    const float* aW2 = (const float*)d_in[4];
    const float* ab2 = (const float*)d_in[5];
    const float* aW3 = (const float*)d_in[6];
    const float* ab3 = (const float*)d_in[7];
    const float* wt  = (const float*)d_in[8];
    const float* sW1 = (const float*)d_in[9];
    const float* sb1 = (const float*)d_in[10];
    const float* sW2 = (const float*)d_in[11];
    const float* sb2 = (const float*)d_in[12];
    const float* sW3 = (const float*)d_in[13];
    const float* sb3 = (const float*)d_in[14];
    float* out = (float*)d_out;

    float* ws = (float*)d_ws;
    const size_t TP = (size_t)T_TOK * HPAD;      // 655360
    float* H1a    = ws;
    float* scores = H1a + TP;
    float* Abuf   = scores + T_TOK;
    float* Bbuf   = Abuf + TP;
    float* Ebuf   = Bbuf + TP;
    float* wcbuf  = Ebuf + TP;
    float* h1sp   = wcbuf + MAXW * HPAD;

    // all per-token projections + width constants in one launch (1280 blocks)
    k_proj<<<dim3(T_TOK / 16, 5), 256, 0, stream>>>(
        states, embeds, aW1, ab1, sW1, wt, sb1, H1a, Abuf, Bbuf, Ebuf, wcbuf);
    // attn layer2 + layer3 -> scores (256 blocks)
    k_attn2<<<T_TOK / 16, 256, 0, stream>>>(H1a, aW2, ab2, aW3, ab3, scores);
    // per-span softmax pooling + layer1 combine (10229 blocks)
    {
        int nblk = (NSPAN * 64 + 255) / 256;
        k_spans<<<nblk, 256, 0, stream>>>(scores, Abuf, Bbuf, Ebuf, wcbuf, h1sp);
    }
    // sm layer2 + fused layer3 -> out (1279 blocks)
    k_final<<<(NSPAN + 31) / 32, 256, 0, stream>>>(h1sp, sW2, sb2, sW3, sb3, out);
}

// Round 3
// 233.712 us; speedup vs baseline: 1.6093x; 1.2363x over previous
//
#include <hip/hip_runtime.h>
#include <hip/hip_bf16.h>

#define T_TOK 4096
#define SDIM  400
#define EDIM  300
#define HID   150
#define HPAD  160
#define NSPAN 40915
#define MAXW  10

// ---------------- fp32 tiled GEMM body: C[M x 150] = act(A[MxK] @ B[Kx150] + bias)
// optional fused layer-3: out[m] = dot(relu(row), w3) + b3
// Block: 256 threads. Tile: MT rows x 150 cols. Per-thread: MT/8 rows x 5 cols.
template <int MT>
__device__ __forceinline__ void gemm_body(
    const float* __restrict__ A, int lda, int relu_a,
    const float* __restrict__ B, int ldb,
    const float* __restrict__ bias, int relu,
    const float* __restrict__ w3, const float* __restrict__ b3,
    float* __restrict__ C, int ldc, int M, int K, int m0,
    float (*As)[MT], float (*Bs)[160], float (*red)[33])
{
    constexpr int R = MT / 8;
    const int tid = threadIdx.x;
    const int r8  = tid >> 5;   // 0..7 row group
    const int c32 = tid & 31;   // 0..31 col lane

    float acc[R][5];
#pragma unroll
    for (int i = 0; i < R; i++)
#pragma unroll
        for (int j = 0; j < 5; j++) acc[i][j] = 0.f;

    const int mrow = tid >> 2;            // staging row (valid if < MT)
    const int kq   = tid & 3;             // staging k-quad
    const bool stage_a = tid < MT * 4;
    const bool mok = stage_a && (m0 + mrow) < M;
    const float* Arow = A + (size_t)(m0 + mrow) * lda;

    for (int k0 = 0; k0 < K; k0 += 16) {
        const int kmax = min(16, K - k0);
        __syncthreads();
        // stage A chunk transposed: As[k][m]
        if (stage_a) {
            float4 v = make_float4(0.f, 0.f, 0.f, 0.f);
            if (mok && kq * 4 < kmax)
                v = *reinterpret_cast<const float4*>(Arow + k0 + kq * 4);
            if (relu_a) {
                v.x = fmaxf(v.x, 0.f); v.y = fmaxf(v.y, 0.f);
                v.z = fmaxf(v.z, 0.f); v.w = fmaxf(v.w, 0.f);
            }
            As[kq * 4 + 0][mrow] = v.x;
            As[kq * 4 + 1][mrow] = v.y;
            As[kq * 4 + 2][mrow] = v.z;
            As[kq * 4 + 3][mrow] = v.w;
        }
        // stage B chunk: Bs[k][c]
#pragma unroll
        for (int it = 0; it < 10; ++it) {
            int idx = tid + it * 256;          // 16*160 = 2560 = 10*256
            int k = idx / 160, c = idx - k * 160;
            float bv = 0.f;
            if (k < kmax && c < HID) bv = B[(size_t)(k0 + k) * ldb + c];
            Bs[k][c] = bv;
        }
        __syncthreads();

        auto step = [&](int kk) {
            float a[R];
#pragma unroll
            for (int i = 0; i < R; i++) a[i] = As[kk][r8 * R + i];
            float b[5];
#pragma unroll
            for (int j = 0; j < 5; j++) b[j] = Bs[kk][c32 + 32 * j];
#pragma unroll
            for (int i = 0; i < R; i++)
#pragma unroll
                for (int j = 0; j < 5; j++)
                    acc[i][j] = fmaf(a[i], b[j], acc[i][j]);
        };
        if (kmax == 16) {
#pragma unroll
            for (int kk = 0; kk < 16; ++kk) step(kk);
        } else {
            for (int kk = 0; kk < kmax; ++kk) step(kk);
        }
    }

    float bv[5];
#pragma unroll
    for (int j = 0; j < 5; j++) {
        int c = c32 + 32 * j;
        bv[j] = (bias != nullptr && c < HID) ? bias[c] : 0.f;
    }

    if (w3 == nullptr) {
#pragma unroll
        for (int i = 0; i < R; i++) {
            int gm = m0 + r8 * R + i;
            if (gm < M) {
#pragma unroll
                for (int j = 0; j < 5; j++) {
                    int c = c32 + 32 * j;
                    if (c < HID) {
                        float v = acc[i][j] + bv[j];
                        if (relu) v = fmaxf(v, 0.f);
                        C[(size_t)gm * ldc + c] = v;
                    }
                }
            }
        }
    } else {
        float w3v[5];
#pragma unroll
        for (int j = 0; j < 5; j++) {
            int c = c32 + 32 * j;
            w3v[j] = (c < HID) ? w3[c] : 0.f;
        }
#pragma unroll
        for (int i = 0; i < R; i++) {
            float p = 0.f;
#pragma unroll
            for (int j = 0; j < 5; j++) {
                float v = fmaxf(acc[i][j] + bv[j], 0.f);   // relu before layer-3
                p = fmaf(v, w3v[j], p);
            }
            red[r8 * R + i][c32] = p;
        }
        __syncthreads();
        if (tid < MT) {
            float s = 0.f;
#pragma unroll
            for (int c = 0; c < 32; c++) s += red[tid][c];
            int gm = m0 + tid;
            if (gm < MT ? (m0 + tid) < M : false) {}
            if ((m0 + tid) < M) C[m0 + tid] = s + b3[0];
        }
    }
}

// init: zero the 4 atomic-accumulated projection buffers + compute width constants
__global__ __launch_bounds__(256) void k_init(
    float* __restrict__ zbase,                 // 4*T_TOK*HPAD floats, contiguous
    const float* __restrict__ wt, const float* __restrict__ sW1,
    const float* __restrict__ sb1, float* __restrict__ wcbuf)
{
    int b = blockIdx.x;
    if (b < 2560) {                            // 2560*256 float4 = 4*655360 floats
        float4* p = reinterpret_cast<float4*>(zbase);
        p[(size_t)b * 256 + threadIdx.x] = make_float4(0.f, 0.f, 0.f, 0.f);
    } else {
        int n = b - 2560 + 1;                  // 1..MAXW
        int c = threadIdx.x;
        if (c < HID) {
            const int dt[11] = {0, 1, 2, 3, 4, 4, 4, 4, 5, 5, 5};
            const float* w = wt + dt[n] * 20;
            float s = sb1[c];
#pragma unroll
            for (int j = 0; j < 20; j++)
                s = fmaf(w[j], sW1[(1100 + j) * HID + c], s);
            wcbuf[(n - 1) * HPAD + c] = s;
        }
    }
}

// split-K projection GEMMs. piece = blockIdx.y: g = piece>>1 in {H1a,A,B,E}, kp = piece&1.
// Accumulate into C via fp32 HW atomics (buffers pre-zeroed). H1a relu deferred.
__global__ __launch_bounds__(256) void k_projsplit(
    const float* __restrict__ states, const float* __restrict__ embeds,
    const float* __restrict__ aW1, const float* __restrict__ ab1,
    const float* __restrict__ sW1,
    float* __restrict__ H1a, float* __restrict__ Abuf,
    float* __restrict__ Bbuf, float* __restrict__ Ebuf)
{
    __shared__ float As[16][32];
    __shared__ float Bs[16][160];

    const int piece = blockIdx.y;
    const int g  = piece >> 1;
    const int kp = piece & 1;
    const int Ktot = (g == 3) ? EDIM : SDIM;
    const int khalf = Ktot / 2;
    const int k0p  = kp * khalf;
    const int klen = khalf;

    const float* A   = (g == 3) ? embeds : states;
    const int    lda = (g == 3) ? EDIM : SDIM;
    const float* B;
    float* C;
    switch (g) {
        case 0: B = aW1;             C = H1a;  break;
        case 1: B = sW1;             C = Abuf; break;
        case 2: B = sW1 + 400 * HID; C = Bbuf; break;
        default:B = sW1 + 800 * HID; C = Ebuf; break;
    }
    const float* bias = (g == 0 && kp == 0) ? ab1 : nullptr;

    const int m0  = blockIdx.x * 32;
    const int tid = threadIdx.x;
    const int r8  = tid >> 5;
    const int c32 = tid & 31;

    float acc[4][5];
#pragma unroll
    for (int i = 0; i < 4; i++)
#pragma unroll
        for (int j = 0; j < 5; j++) acc[i][j] = 0.f;

    const int mrow = tid >> 2;          // 0..63 (use <32)
    const int kq   = tid & 3;
    const bool stage_a = tid < 128;
    const float* Arow = A + (size_t)(m0 + mrow) * lda + k0p;

    for (int k0 = 0; k0 < klen; k0 += 16) {
        const int kmax = min(16, klen - k0);
        __syncthreads();
        if (stage_a) {
            float4 v = make_float4(0.f, 0.f, 0.f, 0.f);
            if (kq * 4 < kmax)
                v = *reinterpret_cast<const float4*>(Arow + k0 + kq * 4);
            As[kq * 4 + 0][mrow] = v.x;
            As[kq * 4 + 1][mrow] = v.y;
            As[kq * 4 + 2][mrow] = v.z;
            As[kq * 4 + 3][mrow] = v.w;
        }
#pragma unroll
        for (int it = 0; it < 10; ++it) {
            int idx = tid + it * 256;
            int k = idx / 160, c = idx - k * 160;
            float bval = 0.f;
            if (k < kmax && c < HID) bval = B[(size_t)(k0p + k0 + k) * HID + c];
            Bs[k][c] = bval;
        }
        __syncthreads();

        auto step = [&](int kk) {
            float a[4];
#pragma unroll
            for (int i = 0; i < 4; i++) a[i] = As[kk][r8 * 4 + i];
            float b[5];
#pragma unroll
            for (int j = 0; j < 5; j++) b[j] = Bs[kk][c32 + 32 * j];
#pragma unroll
            for (int i = 0; i < 4; i++)
#pragma unroll
                for (int j = 0; j < 5; j++)
                    acc[i][j] = fmaf(a[i], b[j], acc[i][j]);
        };
        if (kmax == 16) {
#pragma unroll
            for (int kk = 0; kk < 16; ++kk) step(kk);
        } else {
            for (int kk = 0; kk < kmax; ++kk) step(kk);
        }
    }

#pragma unroll
    for (int j = 0; j < 5; j++) {
        int c = c32 + 32 * j;
        if (c < HID) {
            float bv = (bias != nullptr) ? bias[c] : 0.f;
#pragma unroll
            for (int i = 0; i < 4; i++) {
                int gm = m0 + r8 * 4 + i;
                unsafeAtomicAdd(&C[(size_t)gm * HPAD + c], acc[i][j] + bv);
            }
        }
    }
}

// attn layer2 + fused layer3 -> scores (relu applied to H1a on load)
__global__ __launch_bounds__(256) void k_attn2(
    const float* __restrict__ H1a, const float* __restrict__ aW2,
    const float* __restrict__ ab2, const float* __restrict__ aW3,
    const float* __restrict__ ab3, float* __restrict__ scores)
{
    __shared__ float As[16][16];
    __shared__ float Bs[16][160];
    __shared__ float red[16][33];
    gemm_body<16>(H1a, HPAD, 1, aW2, HID, ab2, 1, aW3, ab3,
                  scores, 0, T_TOK, HID, blockIdx.x * 16, As, Bs, red);
}

// one wave per span: softmax over n scores, h1 = relu(A[s]+B[e]+sum a_i E[s+i]+wc[n])
__global__ __launch_bounds__(256) void k_spans(
    const float* __restrict__ scores, const float* __restrict__ Abuf,
    const float* __restrict__ Bbuf, const float* __restrict__ Ebuf,
    const float* __restrict__ wc, float* __restrict__ h1sp)
{
    int span = (blockIdx.x * 256 + threadIdx.x) >> 6;
    int lane = threadIdx.x & 63;
    if (span >= NSPAN) return;

    int n = 1, base = 0;
#pragma unroll
    for (int i = 1; i <= MAXW; i++) {
        int w = T_TOK - i + 1;
        if (span < base + w) { n = i; break; }
        base += w;
    }
    const int start = span - base;
    const int end   = start + n - 1;

    float sc[MAXW];
#pragma unroll
    for (int i = 0; i < MAXW; i++)
        sc[i] = (i < n) ? scores[start + i] : -1e30f;
    float mx = sc[0];
#pragma unroll
    for (int i = 1; i < MAXW; i++) mx = fmaxf(mx, sc[i]);
    float ssum = 0.f;
#pragma unroll
    for (int i = 0; i < MAXW; i++) { sc[i] = __expf(sc[i] - mx); ssum += sc[i]; }
    const float inv = 1.f / ssum;
#pragma unroll
    for (int i = 0; i < MAXW; i++) sc[i] *= inv;

    const float* Ar  = Abuf + (size_t)start * HPAD;
    const float* Br  = Bbuf + (size_t)end * HPAD;
    const float* wcr = wc + (n - 1) * HPAD;
    float* out = h1sp + (size_t)span * HPAD;
#pragma unroll
    for (int slot = 0; slot < 3; ++slot) {
        int d = lane + slot * 64;
        if (d < HID) {
            float v = Ar[d] + Br[d] + wcr[d];
#pragma unroll
            for (int i = 0; i < MAXW; i++) {
                if (i >= n) break;
                v = fmaf(sc[i], Ebuf[(size_t)(start + i) * HPAD + d], v);
            }
            out[d] = fmaxf(v, 0.f);
        }
    }
}

// sm layer2 + fused layer3 -> out
__global__ __launch_bounds__(256) void k_final(
    const float* __restrict__ h1sp, const float* __restrict__ sW2,
    const float* __restrict__ sb2, const float* __restrict__ sW3,
    const float* __restrict__ sb3, float* __restrict__ out)
{
    __shared__ float As[16][32];
    __shared__ float Bs[16][160];
    __shared__ float red[32][33];
    gemm_body<32>(h1sp, HPAD, 0, sW2, HID, sb2, 1, sW3, sb3,
                  out, 0, NSPAN, HID, blockIdx.x * 32, As, Bs, red);
}

extern "C" void kernel_launch(void* const* d_in, const int* in_sizes, int n_in,
                              void* d_out, int out_size, void* d_ws, size_t ws_size,
                              hipStream_t stream) {
    const float* embeds = (const float*)d_in[0];
    const float* states = (const float*)d_in[1];
    const float* aW1 = (const float*)d_in[2];
    const float* ab1 = (const float*)d_in[3];
    const float* aW2 = (const float*)d_in[4];
    const float* ab2 = (const float*)d_in[5];
    const float* aW3 = (const float*)d_in[6];
    const float* ab3 = (const float*)d_in[7];
    const float* wt  = (const float*)d_in[8];
    const float* sW1 = (const float*)d_in[9];
    const float* sb1 = (const float*)d_in[10];
    const float* sW2 = (const float*)d_in[11];
    const float* sb2 = (const float*)d_in[12];
    const float* sW3 = (const float*)d_in[13];
    const float* sb3 = (const float*)d_in[14];
    float* out = (float*)d_out;

    float* ws = (float*)d_ws;
    const size_t TP = (size_t)T_TOK * HPAD;      // 655360
    float* H1a    = ws;                          // [0, TP)   — contiguous zero region
    float* Abuf   = H1a + TP;                    // [TP, 2TP)
    float* Bbuf   = Abuf + TP;                   // [2TP, 3TP)
    float* Ebuf   = Bbuf + TP;                   // [3TP, 4TP)
    float* scores = Ebuf + TP;
    float* wcbuf  = scores + T_TOK;
    float* h1sp   = wcbuf + MAXW * HPAD;

    // zero the atomic buffers + width constants (2570 blocks)
    k_init<<<2560 + MAXW, 256, 0, stream>>>(H1a, wt, sW1, sb1, wcbuf);
    // split-K projections: 128 tiles x 8 pieces = 1024 blocks
    k_projsplit<<<dim3(T_TOK / 32, 8), 256, 0, stream>>>(
        states, embeds, aW1, ab1, sW1, H1a, Abuf, Bbuf, Ebuf);
    // attn layer2 + layer3 -> scores (256 blocks)
    k_attn2<<<T_TOK / 16, 256, 0, stream>>>(H1a, aW2, ab2, aW3, ab3, scores);
    // per-span softmax pooling + layer1 combine (10229 blocks)
    {
        int nblk = (NSPAN * 64 + 255) / 256;
        k_spans<<<nblk, 256, 0, stream>>>(scores, Abuf, Bbuf, Ebuf, wcbuf, h1sp);
    }
    // sm layer2 + fused layer3 -> out (1279 blocks)
    k_final<<<(NSPAN + 31) / 32, 256, 0, stream>>>(h1sp, sW2, sb2, sW3, sb3, out);
}

// Round 4
// 89.599 us; speedup vs baseline: 4.1977x; 2.6084x over previous
//
#include <hip/hip_runtime.h>
#include <hip/hip_bf16.h>

#define T_TOK 4096
#define HID   150
#define HPAD  160
#define NSPAN 40915
#define MAXW  10
#define MP    40928          // NSPAN padded to multiple of 16
#define NT    10             // 160/16 col tiles

typedef __attribute__((ext_vector_type(8))) short bf16x8;
typedef __attribute__((ext_vector_type(4))) float f32x4;

static __device__ __forceinline__ unsigned short bf_rne(float f) {
    unsigned int u = __float_as_uint(f);
    unsigned int r = (u + 0x7FFFu + ((u >> 16) & 1u)) >> 16;
    return (unsigned short)r;
}
static __device__ __forceinline__ float bf_tof(unsigned short h) {
    return __uint_as_float(((unsigned int)h) << 16);
}
static __device__ __forceinline__ uint4 pack8(const unsigned short* a) {
    uint4 r;
    r.x = (unsigned)a[0] | ((unsigned)a[1] << 16);
    r.y = (unsigned)a[2] | ((unsigned)a[3] << 16);
    r.z = (unsigned)a[4] | ((unsigned)a[5] << 16);
    r.w = (unsigned)a[6] | ((unsigned)a[7] << 16);
    return r;
}

// width constants: wc[n-1][c] = sb1[c] + sum_j wt[dtoi(n)][j]*sW1[1100+j][c]; pad cols = 0
__global__ __launch_bounds__(192) void k_init(
    const float* __restrict__ wt, const float* __restrict__ sW1,
    const float* __restrict__ sb1, float* __restrict__ wc)
{
    int n = blockIdx.x + 1, c = threadIdx.x;
    if (c >= HPAD) return;
    float s = 0.f;
    if (c < HID) {
        const int dt[11] = {0, 1, 2, 3, 4, 4, 4, 4, 5, 5, 5};
        const float* ww = wt + dt[n] * 20;
        s = sb1[c];
#pragma unroll
        for (int j = 0; j < 20; j++) s = fmaf(ww[j], sW1[(1100 + j) * HID + c], s);
    }
    wc[(n - 1) * HPAD + c] = s;
}

// weights -> B-frag hi/lo (zero-padded). frag slot = ((kt*NT+nt)*64 + lane)*8 + e
// lane: n = nt*16 + (l&15), k = kt*32 + (l>>4)*8 + e
__global__ __launch_bounds__(256) void k_cvtB(
    const float* __restrict__ aW1, const float* __restrict__ sW1,
    const float* __restrict__ aW2, const float* __restrict__ sW2,
    unsigned short* __restrict__ fW1h, unsigned short* __restrict__ fW1l,
    unsigned short* __restrict__ fA1h, unsigned short* __restrict__ fA1l,
    unsigned short* __restrict__ fB1h, unsigned short* __restrict__ fB1l,
    unsigned short* __restrict__ fE1h, unsigned short* __restrict__ fE1l,
    unsigned short* __restrict__ fA2h, unsigned short* __restrict__ fA2l,
    unsigned short* __restrict__ fW2h, unsigned short* __restrict__ fW2l)
{
    const float* src; int srcK, KT; unsigned short *dh, *dl;
    switch (blockIdx.y) {
        case 0: src = aW1;             srcK = 400; KT = 13; dh = fW1h; dl = fW1l; break;
        case 1: src = sW1;             srcK = 400; KT = 13; dh = fA1h; dl = fA1l; break;
        case 2: src = sW1 + 400 * HID; srcK = 400; KT = 13; dh = fB1h; dl = fB1l; break;
        case 3: src = sW1 + 800 * HID; srcK = 300; KT = 10; dh = fE1h; dl = fE1l; break;
        case 4: src = aW2;             srcK = 150; KT = 5;  dh = fA2h; dl = fA2l; break;
        default:src = sW2;             srcK = 150; KT = 5;  dh = fW2h; dl = fW2l; break;
    }
    int w = threadIdx.x >> 6, l = threadIdx.x & 63;
    int tb = blockIdx.x * 4 + w;
    if (tb >= KT * NT) return;
    int kt = tb / NT, nt = tb - kt * NT;
    int n = nt * 16 + (l & 15);
    int kbase = kt * 32 + (l >> 4) * 8;
    unsigned short hv[8], lv[8];
#pragma unroll
    for (int e = 0; e < 8; e++) {
        int k = kbase + e;
        float f = (k < srcK && n < HID) ? src[(size_t)k * HID + n] : 0.f;
        unsigned short h = bf_rne(f);
        hv[e] = h;
        lv[e] = bf_rne(f - bf_tof(h));
    }
    size_t slot = ((size_t)tb * 64 + l) * 8;
    *(uint4*)(dh + slot) = pack8(hv);
    *(uint4*)(dl + slot) = pack8(lv);
}

// activations -> A-frag hi/lo. sel: 0 states(K400->416), 1 embeds(300->320), 2 H1a(relu,160)
// frag slot = ((mt*KT+kt)*64 + lane)*8 + e ; lane: m = mt*16+(l&15), k = kt*32+(l>>4)*8+e
__global__ __launch_bounds__(256) void k_cvtA(
    int sel0,
    const float* __restrict__ states, const float* __restrict__ embeds,
    const float* __restrict__ H1a,
    unsigned short* __restrict__ Sh, unsigned short* __restrict__ Sl,
    unsigned short* __restrict__ Eh, unsigned short* __restrict__ El,
    unsigned short* __restrict__ Hh, unsigned short* __restrict__ Hl)
{
    int sel = sel0 + blockIdx.y;
    const float* src; int lda, srcK, KT, relu;
    unsigned short *dh, *dl;
    switch (sel) {
        case 0:  src = states; lda = 400; srcK = 400; KT = 13; relu = 0; dh = Sh; dl = Sl; break;
        case 1:  src = embeds; lda = 300; srcK = 300; KT = 10; relu = 0; dh = Eh; dl = El; break;
        default: src = H1a;    lda = 160; srcK = 160; KT = 5;  relu = 1; dh = Hh; dl = Hl; break;
    }
    int w = threadIdx.x >> 6, l = threadIdx.x & 63;
    int tb = blockIdx.x * 4 + w;
    if (tb >= 256 * KT) return;
    int mt = tb / KT;
    int m = mt * 16 + (l & 15);
    int kbase = (tb - mt * KT) * 32 + (l >> 4) * 8;
    const float* row = src + (size_t)m * lda;
    unsigned short hv[8], lv[8];
#pragma unroll
    for (int e = 0; e < 8; e++) {
        int k = kbase + e;
        float f = (k < srcK) ? row[k] : 0.f;
        if (relu) f = fmaxf(f, 0.f);
        unsigned short h = bf_rne(f);
        hv[e] = h;
        lv[e] = bf_rne(f - bf_tof(h));
    }
    size_t slot = ((size_t)tb * 64 + l) * 8;
    *(uint4*)(dh + slot) = pack8(hv);
    *(uint4*)(dl + slot) = pack8(lv);
}

// projection GEMMs (hi/lo 3-pass MFMA, no LDS). y: 0 H1a(+ab1), 1 Abuf, 2 Bbuf, 3 Ebuf
// block 256 = 4 waves: wave = (mtile pair half, n half). Block tile 32 x 160.
__global__ __launch_bounds__(256) void k_proj(
    const unsigned short* __restrict__ Sh, const unsigned short* __restrict__ Sl,
    const unsigned short* __restrict__ Eh, const unsigned short* __restrict__ El,
    const unsigned short* __restrict__ fW1h, const unsigned short* __restrict__ fW1l,
    const unsigned short* __restrict__ fA1h, const unsigned short* __restrict__ fA1l,
    const unsigned short* __restrict__ fB1h, const unsigned short* __restrict__ fB1l,
    const unsigned short* __restrict__ fE1h, const unsigned short* __restrict__ fE1l,
    const float* __restrict__ ab1,
    float* __restrict__ H1a, float* __restrict__ Abuf,
    float* __restrict__ Bbuf, float* __restrict__ Ebuf)
{
    const unsigned short *Ah_, *Al_, *Bh_, *Bl_; int KT; float* C; int hasBias = 0;
    switch (blockIdx.y) {
        case 0: Ah_=Sh; Al_=Sl; Bh_=fW1h; Bl_=fW1l; KT=13; C=H1a;  hasBias=1; break;
        case 1: Ah_=Sh; Al_=Sl; Bh_=fA1h; Bl_=fA1l; KT=13; C=Abuf; break;
        case 2: Ah_=Sh; Al_=Sl; Bh_=fB1h; Bl_=fB1l; KT=13; C=Bbuf; break;
        default:Ah_=Eh; Al_=El; Bh_=fE1h; Bl_=fE1l; KT=10; C=Ebuf; break;
    }
    const int w = threadIdx.x >> 6, l = threadIdx.x & 63;
    const int mt = blockIdx.x * 2 + (w >> 1);
    const int nh = w & 1;
    const bf16x8* pAh = (const bf16x8*)Ah_;
    const bf16x8* pAl = (const bf16x8*)Al_;
    const bf16x8* pBh = (const bf16x8*)Bh_;
    const bf16x8* pBl = (const bf16x8*)Bl_;

    f32x4 acc[5];
#pragma unroll
    for (int c = 0; c < 5; c++) acc[c] = (f32x4){0.f, 0.f, 0.f, 0.f};

#pragma unroll 2
    for (int kt = 0; kt < KT; ++kt) {
        bf16x8 ah = pAh[(size_t)(mt * KT + kt) * 64 + l];
        bf16x8 al = pAl[(size_t)(mt * KT + kt) * 64 + l];
#pragma unroll
        for (int c = 0; c < 5; c++) {
            int ct = nh * 5 + c;
            bf16x8 bh = pBh[(size_t)(kt * NT + ct) * 64 + l];
            bf16x8 bl = pBl[(size_t)(kt * NT + ct) * 64 + l];
            acc[c] = __builtin_amdgcn_mfma_f32_16x16x32_bf16(ah, bh, acc[c], 0, 0, 0);
            acc[c] = __builtin_amdgcn_mfma_f32_16x16x32_bf16(al, bh, acc[c], 0, 0, 0);
            acc[c] = __builtin_amdgcn_mfma_f32_16x16x32_bf16(ah, bl, acc[c], 0, 0, 0);
        }
    }
    const int m0 = mt * 16;
#pragma unroll
    for (int c = 0; c < 5; c++) {
        int col = (nh * 5 + c) * 16 + (l & 15);
        float bb = (hasBias && col < HID) ? ab1[col] : 0.f;
#pragma unroll
        for (int r = 0; r < 4; r++) {
            int row = m0 + (l >> 4) * 4 + r;
            C[(size_t)row * HPAD + col] = acc[c][r] + bb;
        }
    }
}

// GEMM(K=160) + bias + relu + fused dot(w3) + b3 -> out[row]. Used for attn scores and final.
__global__ __launch_bounds__(256) void k_head(
    const unsigned short* __restrict__ Ah_, const unsigned short* __restrict__ Al_,
    const unsigned short* __restrict__ Bh_, const unsigned short* __restrict__ Bl_,
    const float* __restrict__ bias, const float* __restrict__ w3,
    const float* __restrict__ b3, float* __restrict__ out,
    int mtiles, int Mreal)
{
    __shared__ float red[4][16];
    const int w = threadIdx.x >> 6, l = threadIdx.x & 63;
    const int mt = blockIdx.x * 2 + (w >> 1);
    const int nh = w & 1;
    const bf16x8* pAh = (const bf16x8*)Ah_;
    const bf16x8* pAl = (const bf16x8*)Al_;
    const bf16x8* pBh = (const bf16x8*)Bh_;
    const bf16x8* pBl = (const bf16x8*)Bl_;

    f32x4 acc[5];
#pragma unroll
    for (int c = 0; c < 5; c++) acc[c] = (f32x4){0.f, 0.f, 0.f, 0.f};

    if (mt < mtiles) {
#pragma unroll
        for (int kt = 0; kt < 5; ++kt) {
            bf16x8 ah = pAh[(size_t)(mt * 5 + kt) * 64 + l];
            bf16x8 al = pAl[(size_t)(mt * 5 + kt) * 64 + l];
#pragma unroll
            for (int c = 0; c < 5; c++) {
                int ct = nh * 5 + c;
                bf16x8 bh = pBh[(size_t)(kt * NT + ct) * 64 + l];
                bf16x8 bl = pBl[(size_t)(kt * NT + ct) * 64 + l];
                acc[c] = __builtin_amdgcn_mfma_f32_16x16x32_bf16(ah, bh, acc[c], 0, 0, 0);
                acc[c] = __builtin_amdgcn_mfma_f32_16x16x32_bf16(al, bh, acc[c], 0, 0, 0);
                acc[c] = __builtin_amdgcn_mfma_f32_16x16x32_bf16(ah, bl, acc[c], 0, 0, 0);
            }
        }
    }
    float p[4] = {0.f, 0.f, 0.f, 0.f};
    if (mt < mtiles) {
#pragma unroll
        for (int c = 0; c < 5; c++) {
            int col = (nh * 5 + c) * 16 + (l & 15);
            float bb = (col < HID) ? bias[col] : 0.f;
            float wv = (col < HID) ? w3[col] : 0.f;
#pragma unroll
            for (int r = 0; r < 4; r++) {
                float v = fmaxf(acc[c][r] + bb, 0.f);
                p[r] = fmaf(v, wv, p[r]);
            }
        }
    }
#pragma unroll
    for (int off = 1; off < 16; off <<= 1)
#pragma unroll
        for (int r = 0; r < 4; r++) p[r] += __shfl_xor(p[r], off);
    if ((l & 15) == 0)
#pragma unroll
        for (int r = 0; r < 4; r++) red[w][(l >> 4) * 4 + r] = p[r];
    __syncthreads();
    if (threadIdx.x < 32) {
        int ml = threadIdx.x;
        int row = blockIdx.x * 32 + ml;
        if (row < Mreal)
            out[row] = red[(ml >> 4) * 2 + 0][ml & 15] + red[(ml >> 4) * 2 + 1][ml & 15] + b3[0];
    }
}

// per-span softmax pooling + layer-1 combine; writes h1 directly as A-frag hi/lo
__global__ __launch_bounds__(256) void k_spans(
    const float* __restrict__ scores, const float* __restrict__ Abuf,
    const float* __restrict__ Bbuf, const float* __restrict__ Ebuf,
    const float* __restrict__ wc,
    unsigned short* __restrict__ h1h, unsigned short* __restrict__ h1l)
{
    const int w = threadIdx.x >> 6, q = threadIdx.x & 63;
    const int span = blockIdx.x * 4 + w;
    if (q >= 40 || span >= MP) return;

    float v0 = 0.f, v1 = 0.f, v2 = 0.f, v3 = 0.f;
    if (span < NSPAN) {
        int n = 1, base = 0;
#pragma unroll
        for (int i = 1; i <= MAXW; i++) {
            int ww = T_TOK - i + 1;
            if (span < base + ww) { n = i; break; }
            base += ww;
        }
        const int start = span - base;

        float sc[MAXW]; float mx = -1e30f;
#pragma unroll
        for (int i = 0; i < MAXW; i++) {
            sc[i] = (i < n) ? scores[start + i] : -1e30f;
            mx = fmaxf(mx, sc[i]);
        }
        float ssum = 0.f;
#pragma unroll
        for (int i = 0; i < MAXW; i++) { sc[i] = __expf(sc[i] - mx); ssum += sc[i]; }
        const float inv = 1.f / ssum;

        const int d0 = q * 4;
        if (d0 < HID) {
            const int endr = start + n - 1;
            float4 a4 = *(const float4*)(Abuf + (size_t)start * HPAD + d0);
            float4 b4 = *(const float4*)(Bbuf + (size_t)endr * HPAD + d0);
            float4 w4 = *(const float4*)(wc + (n - 1) * HPAD + d0);
            v0 = a4.x + b4.x + w4.x; v1 = a4.y + b4.y + w4.y;
            v2 = a4.z + b4.z + w4.z; v3 = a4.w + b4.w + w4.w;
            for (int i = 0; i < n; i++) {
                float4 e4 = *(const float4*)(Ebuf + (size_t)(start + i) * HPAD + d0);
                float a = sc[i] * inv;
                v0 = fmaf(a, e4.x, v0); v1 = fmaf(a, e4.y, v1);
                v2 = fmaf(a, e4.z, v2); v3 = fmaf(a, e4.w, v3);
            }
            v0 = fmaxf(v0, 0.f); v1 = fmaxf(v1, 0.f);
            v2 = fmaxf(v2, 0.f); v3 = fmaxf(v3, 0.f);
        }
    }
    // frag write: d = 4q; kt = q>>3, g = (q>>1)&3, e0 = (q&1)*4; lane_f = g*16 + (span&15)
    const int mt = span >> 4, sm = span & 15;
    const int kt = q >> 3, gg = (q >> 1) & 3, e0 = (q & 1) * 4;
    size_t slot = ((size_t)(mt * 5 + kt) * 64 + gg * 16 + sm) * 8 + e0;
    unsigned short h0 = bf_rne(v0), h1_ = bf_rne(v1), h2_ = bf_rne(v2), h3_ = bf_rne(v3);
    ushort4 hv, lv;
    hv.x = h0; hv.y = h1_; hv.z = h2_; hv.w = h3_;
    lv.x = bf_rne(v0 - bf_tof(h0)); lv.y = bf_rne(v1 - bf_tof(h1_));
    lv.z = bf_rne(v2 - bf_tof(h2_)); lv.w = bf_rne(v3 - bf_tof(h3_));
    *(ushort4*)(h1h + slot) = hv;
    *(ushort4*)(h1l + slot) = lv;
}

extern "C" void kernel_launch(void* const* d_in, const int* in_sizes, int n_in,
                              void* d_out, int out_size, void* d_ws, size_t ws_size,
                              hipStream_t stream) {
    const float* embeds = (const float*)d_in[0];
    const float* states = (const float*)d_in[1];
    const float* aW1 = (const float*)d_in[2];
    const float* ab1 = (const float*)d_in[3];
    const float* aW2 = (const float*)d_in[4];
    const float* ab2 = (const float*)d_in[5];
    const float* aW3 = (const float*)d_in[6];
    const float* ab3 = (const float*)d_in[7];
    const float* wt  = (const float*)d_in[8];
    const float* sW1 = (const float*)d_in[9];
    const float* sb1 = (const float*)d_in[10];
    const float* sW2 = (const float*)d_in[11];
    const float* sb2 = (const float*)d_in[12];
    const float* sW3 = (const float*)d_in[13];
    const float* sb3 = (const float*)d_in[14];
    float* out = (float*)d_out;

    char* W = (char*)d_ws;
    float* H1a    = (float*)(W + 0);            // 4096*160*4 = 2621440
    float* Abuf   = (float*)(W + 2621440);
    float* Bbuf   = (float*)(W + 5242880);
    float* Ebuf   = (float*)(W + 7864320);
    float* scores = (float*)(W + 10485760);     // 16384
    float* wcbuf  = (float*)(W + 10502144);     // 6400
    unsigned short* fW2h = (unsigned short*)(W + 10508544);   // 160*160*2 = 51200
    unsigned short* fW2l = (unsigned short*)(W + 10559744);
    const size_t V = 10610944;                  // volatile region (phase overlay)
    unsigned short* Sh  = (unsigned short*)(W + V);              // 4096*416*2 = 3407872
    unsigned short* Sl  = (unsigned short*)(W + V + 3407872);
    unsigned short* Eh  = (unsigned short*)(W + V + 6815744);    // 4096*320*2 = 2621440
    unsigned short* El  = (unsigned short*)(W + V + 9437184);
    unsigned short* Hh  = (unsigned short*)(W + V + 12058624);   // 4096*160*2 = 1310720
    unsigned short* Hl  = (unsigned short*)(W + V + 13369344);
    unsigned short* fW1h= (unsigned short*)(W + V + 14680064);   // 416*160*2 = 133120
    unsigned short* fW1l= (unsigned short*)(W + V + 14813184);
    unsigned short* fA1h= (unsigned short*)(W + V + 14946304);
    unsigned short* fA1l= (unsigned short*)(W + V + 15079424);
    unsigned short* fB1h= (unsigned short*)(W + V + 15212544);
    unsigned short* fB1l= (unsigned short*)(W + V + 15345664);
    unsigned short* fE1h= (unsigned short*)(W + V + 15478784);   // 320*160*2 = 102400
    unsigned short* fE1l= (unsigned short*)(W + V + 15581184);
    unsigned short* fA2h= (unsigned short*)(W + V + 15683584);   // 160*160*2 = 51200
    unsigned short* fA2l= (unsigned short*)(W + V + 15734784);
    // phase-2 overlay (after attn2 no earlier frags are read):
    unsigned short* h1h = (unsigned short*)(W + V);              // 40928*160*2 = 13096960
    unsigned short* h1l = (unsigned short*)(W + V + 13096960);

    // width constants
    k_init<<<MAXW, 192, 0, stream>>>(wt, sW1, sb1, wcbuf);
    // weights -> frags (6 tensors)
    k_cvtB<<<dim3(33, 6), 256, 0, stream>>>(aW1, sW1, aW2, sW2,
        fW1h, fW1l, fA1h, fA1l, fB1h, fB1l, fE1h, fE1l, fA2h, fA2l, fW2h, fW2l);
    // states + embeds -> frags
    k_cvtA<<<dim3(832, 2), 256, 0, stream>>>(0, states, embeds, H1a,
                                             Sh, Sl, Eh, El, Hh, Hl);
    // 4 projection GEMMs
    k_proj<<<dim3(128, 4), 256, 0, stream>>>(Sh, Sl, Eh, El,
        fW1h, fW1l, fA1h, fA1l, fB1h, fB1l, fE1h, fE1l, ab1,
        H1a, Abuf, Bbuf, Ebuf);
    // relu(H1a) -> frags
    k_cvtA<<<dim3(320, 1), 256, 0, stream>>>(2, states, embeds, H1a,
                                             Sh, Sl, Eh, El, Hh, Hl);
    // attn layer2+3 -> scores
    k_head<<<128, 256, 0, stream>>>(Hh, Hl, fA2h, fA2l, ab2, aW3, ab3,
                                    scores, 256, T_TOK);
    // spans -> h1 frags
    k_spans<<<MP / 4, 256, 0, stream>>>(scores, Abuf, Bbuf, Ebuf, wcbuf, h1h, h1l);
    // sm layer2+3 -> out
    k_head<<<1279, 256, 0, stream>>>(h1h, h1l, fW2h, fW2l, sb2, sW3, sb3,
                                     out, 2558, NSPAN);
}

// Round 5
// 63.656 us; speedup vs baseline: 5.9084x; 1.4075x over previous
//
#include <hip/hip_runtime.h>
#include <hip/hip_bf16.h>

#define T_TOK 4096
#define HID   150
#define HPAD  160
#define NSPAN 40915
#define MAXW  10
#define NT    10             // 160/16 col tiles

typedef __attribute__((ext_vector_type(8))) short bf16x8;
typedef __attribute__((ext_vector_type(4))) float f32x4;

static __device__ __forceinline__ unsigned short bf_rne(float f) {
    unsigned int u = __float_as_uint(f);
    unsigned int r = (u + 0x7FFFu + ((u >> 16) & 1u)) >> 16;
    return (unsigned short)r;
}
static __device__ __forceinline__ float bf_tof(unsigned short h) {
    return __uint_as_float(((unsigned int)h) << 16);
}
static __device__ __forceinline__ uint4 pack8(const unsigned short* a) {
    uint4 r;
    r.x = (unsigned)a[0] | ((unsigned)a[1] << 16);
    r.y = (unsigned)a[2] | ((unsigned)a[3] << 16);
    r.z = (unsigned)a[4] | ((unsigned)a[5] << 16);
    r.w = (unsigned)a[6] | ((unsigned)a[7] << 16);
    return r;
}

// ---------------- k_prep: all conversions + width constants, one flat grid of 1630 blocks
// [0,832)    states -> A-frags (KT=13)
// [832,1472) embeds -> A-frags (KT=10)
// [1472,1620) 6 weight tensors -> B-frags (590 tile-blocks)
// [1620,1630) width constants
__global__ __launch_bounds__(256) void k_prep(
    const float* __restrict__ states, const float* __restrict__ embeds,
    const float* __restrict__ aW1, const float* __restrict__ sW1,
    const float* __restrict__ aW2, const float* __restrict__ sW2,
    const float* __restrict__ wt, const float* __restrict__ sb1,
    unsigned short* __restrict__ Sh, unsigned short* __restrict__ Sl,
    unsigned short* __restrict__ Eh, unsigned short* __restrict__ El,
    unsigned short* __restrict__ fW1h, unsigned short* __restrict__ fW1l,
    unsigned short* __restrict__ fA1h, unsigned short* __restrict__ fA1l,
    unsigned short* __restrict__ fB1h, unsigned short* __restrict__ fB1l,
    unsigned short* __restrict__ fE1h, unsigned short* __restrict__ fE1l,
    unsigned short* __restrict__ fA2h, unsigned short* __restrict__ fA2l,
    unsigned short* __restrict__ fW2h, unsigned short* __restrict__ fW2l,
    float* __restrict__ wc)
{
    const int b = blockIdx.x;
    const int w = threadIdx.x >> 6, l = threadIdx.x & 63;

    if (b < 1472) {
        // activations -> A-frag hi/lo
        const float* src; int lda, srcK, KT; unsigned short *dh, *dl; int tb;
        if (b < 832) { src = states; lda = 400; srcK = 400; KT = 13; dh = Sh; dl = Sl; tb = b * 4 + w; }
        else         { src = embeds; lda = 300; srcK = 300; KT = 10; dh = Eh; dl = El; tb = (b - 832) * 4 + w; }
        int mt = tb / KT;
        int m = mt * 16 + (l & 15);
        int kbase = (tb - mt * KT) * 32 + (l >> 4) * 8;
        const float* row = src + (size_t)m * lda;
        unsigned short hv[8], lv[8];
#pragma unroll
        for (int e = 0; e < 8; e++) {
            int k = kbase + e;
            float f = (k < srcK) ? row[k] : 0.f;
            unsigned short h = bf_rne(f);
            hv[e] = h;
            lv[e] = bf_rne(f - bf_tof(h));
        }
        size_t slot = ((size_t)tb * 64 + l) * 8;
        *(uint4*)(dh + slot) = pack8(hv);
        *(uint4*)(dl + slot) = pack8(lv);
    } else if (b < 1620) {
        // weights -> B-frag hi/lo
        int tw = (b - 1472) * 4 + w;
        if (tw >= 590) return;
        const float* src; int srcK, off; unsigned short *dh, *dl;
        if      (tw < 130) { src = aW1;             srcK = 400; off = 0;   dh = fW1h; dl = fW1l; }
        else if (tw < 260) { src = sW1;             srcK = 400; off = 130; dh = fA1h; dl = fA1l; }
        else if (tw < 390) { src = sW1 + 400 * HID; srcK = 400; off = 260; dh = fB1h; dl = fB1l; }
        else if (tw < 490) { src = sW1 + 800 * HID; srcK = 300; off = 390; dh = fE1h; dl = fE1l; }
        else if (tw < 540) { src = aW2;             srcK = 150; off = 490; dh = fA2h; dl = fA2l; }
        else               { src = sW2;             srcK = 150; off = 540; dh = fW2h; dl = fW2l; }
        int tb = tw - off;
        int kt = tb / NT, nt = tb - kt * NT;
        int n = nt * 16 + (l & 15);
        int kbase = kt * 32 + (l >> 4) * 8;
        unsigned short hv[8], lv[8];
#pragma unroll
        for (int e = 0; e < 8; e++) {
            int k = kbase + e;
            float f = (k < srcK && n < HID) ? src[(size_t)k * HID + n] : 0.f;
            unsigned short h = bf_rne(f);
            hv[e] = h;
            lv[e] = bf_rne(f - bf_tof(h));
        }
        size_t slot = ((size_t)tb * 64 + l) * 8;
        *(uint4*)(dh + slot) = pack8(hv);
        *(uint4*)(dl + slot) = pack8(lv);
    } else {
        // width constants: wc[n-1][c] = sb1[c] + sum_j wt[dtoi(n)][j]*sW1[1100+j][c]
        int n = b - 1619;            // 1..10
        int c = threadIdx.x;
        if (c >= HPAD) return;
        float s = 0.f;
        if (c < HID) {
            const int dt[11] = {0, 1, 2, 3, 4, 4, 4, 4, 5, 5, 5};
            const float* ww = wt + dt[n] * 20;
            s = sb1[c];
#pragma unroll
            for (int j = 0; j < 20; j++) s = fmaf(ww[j], sW1[(1100 + j) * HID + c], s);
        }
        wc[(n - 1) * HPAD + c] = s;
    }
}

// ---------------- k_proj: grid (128, 4). Block tile 32 x 160, 4 waves.
// y=0: states @ aW1 -> relu -> LDS frags -> @ aW2 -> relu -> dot(aW3) -> scores  (fully fused attn)
// y=1,2,3: states/embeds projections -> Abuf/Bbuf/Ebuf (fp32)
__global__ __launch_bounds__(256) void k_proj(
    const unsigned short* __restrict__ Sh, const unsigned short* __restrict__ Sl,
    const unsigned short* __restrict__ Eh, const unsigned short* __restrict__ El,
    const unsigned short* __restrict__ fW1h, const unsigned short* __restrict__ fW1l,
    const unsigned short* __restrict__ fA1h, const unsigned short* __restrict__ fA1l,
    const unsigned short* __restrict__ fB1h, const unsigned short* __restrict__ fB1l,
    const unsigned short* __restrict__ fE1h, const unsigned short* __restrict__ fE1l,
    const unsigned short* __restrict__ fA2h, const unsigned short* __restrict__ fA2l,
    const float* __restrict__ ab1, const float* __restrict__ ab2,
    const float* __restrict__ aW3, const float* __restrict__ ab3,
    float* __restrict__ Abuf, float* __restrict__ Bbuf, float* __restrict__ Ebuf,
    float* __restrict__ scores)
{
    __shared__ alignas(16) unsigned short hh[5120];   // 2 mtiles x 5 kt x 64 x 8
    __shared__ alignas(16) unsigned short hl[5120];
    __shared__ float red[4][16];

    const unsigned short *Ah_, *Al_, *Bh_, *Bl_; int KT; float* C = nullptr;
    switch (blockIdx.y) {
        case 0: Ah_=Sh; Al_=Sl; Bh_=fW1h; Bl_=fW1l; KT=13; break;
        case 1: Ah_=Sh; Al_=Sl; Bh_=fA1h; Bl_=fA1l; KT=13; C=Abuf; break;
        case 2: Ah_=Sh; Al_=Sl; Bh_=fB1h; Bl_=fB1l; KT=13; C=Bbuf; break;
        default:Ah_=Eh; Al_=El; Bh_=fE1h; Bl_=fE1l; KT=10; C=Ebuf; break;
    }
    const int w = threadIdx.x >> 6, l = threadIdx.x & 63;
    const int mtl = w >> 1;                    // local mtile 0/1
    const int mt  = blockIdx.x * 2 + mtl;
    const int nh  = w & 1;
    const bf16x8* pAh = (const bf16x8*)Ah_;
    const bf16x8* pAl = (const bf16x8*)Al_;
    const bf16x8* pBh = (const bf16x8*)Bh_;
    const bf16x8* pBl = (const bf16x8*)Bl_;

    f32x4 acc[5];
#pragma unroll
    for (int c = 0; c < 5; c++) acc[c] = (f32x4){0.f, 0.f, 0.f, 0.f};

#pragma unroll 2
    for (int kt = 0; kt < KT; ++kt) {
        bf16x8 ah = pAh[(size_t)(mt * KT + kt) * 64 + l];
        bf16x8 al = pAl[(size_t)(mt * KT + kt) * 64 + l];
#pragma unroll
        for (int c = 0; c < 5; c++) {
            int ct = nh * 5 + c;
            bf16x8 bh = pBh[(size_t)(kt * NT + ct) * 64 + l];
            bf16x8 bl = pBl[(size_t)(kt * NT + ct) * 64 + l];
            acc[c] = __builtin_amdgcn_mfma_f32_16x16x32_bf16(ah, bh, acc[c], 0, 0, 0);
            acc[c] = __builtin_amdgcn_mfma_f32_16x16x32_bf16(al, bh, acc[c], 0, 0, 0);
            acc[c] = __builtin_amdgcn_mfma_f32_16x16x32_bf16(ah, bl, acc[c], 0, 0, 0);
        }
    }

    if (blockIdx.y != 0) {
        const int m0 = mt * 16;
#pragma unroll
        for (int c = 0; c < 5; c++) {
            int col = (nh * 5 + c) * 16 + (l & 15);
#pragma unroll
            for (int r = 0; r < 4; r++) {
                int row = m0 + (l >> 4) * 4 + r;
                C[(size_t)row * HPAD + col] = acc[c][r];
            }
        }
        return;
    }

    // ---- fused attention: relu(H1 + ab1) -> LDS frags
    const int m15 = l & 15;
#pragma unroll
    for (int c = 0; c < 5; c++) {
        int u   = nh * 5 + c;
        int col = u * 16 + m15;
        float bb = (col < HID) ? ab1[col] : 0.f;
        int kt = u >> 1;
        int g  = (u & 1) * 2 + (m15 >> 3);
        int e  = m15 & 7;
#pragma unroll
        for (int r = 0; r < 4; r++) {
            int rloc = (l >> 4) * 4 + r;
            float v = fmaxf(acc[c][r] + bb, 0.f);
            unsigned short h = bf_rne(v);
            int slot = ((mtl * 5 + kt) * 64 + g * 16 + rloc) * 8 + e;
            hh[slot] = h;
            hl[slot] = bf_rne(v - bf_tof(h));
        }
    }
    __syncthreads();

    // ---- layer2 GEMM (K=160) from LDS frags vs fA2, + relu + dot(aW3)
    const bf16x8* pHh = (const bf16x8*)hh;
    const bf16x8* pHl = (const bf16x8*)hl;
    f32x4 acc2[5];
#pragma unroll
    for (int c = 0; c < 5; c++) acc2[c] = (f32x4){0.f, 0.f, 0.f, 0.f};
    const bf16x8* pB2h = (const bf16x8*)fA2h;
    const bf16x8* pB2l = (const bf16x8*)fA2l;
#pragma unroll
    for (int kt = 0; kt < 5; ++kt) {
        bf16x8 ah = pHh[(mtl * 5 + kt) * 64 + l];
        bf16x8 al = pHl[(mtl * 5 + kt) * 64 + l];
#pragma unroll
        for (int c = 0; c < 5; c++) {
            int ct = nh * 5 + c;
            bf16x8 bh = pB2h[(size_t)(kt * NT + ct) * 64 + l];
            bf16x8 bl = pB2l[(size_t)(kt * NT + ct) * 64 + l];
            acc2[c] = __builtin_amdgcn_mfma_f32_16x16x32_bf16(ah, bh, acc2[c], 0, 0, 0);
            acc2[c] = __builtin_amdgcn_mfma_f32_16x16x32_bf16(al, bh, acc2[c], 0, 0, 0);
            acc2[c] = __builtin_amdgcn_mfma_f32_16x16x32_bf16(ah, bl, acc2[c], 0, 0, 0);
        }
    }
    float p[4] = {0.f, 0.f, 0.f, 0.f};
#pragma unroll
    for (int c = 0; c < 5; c++) {
        int col = (nh * 5 + c) * 16 + m15;
        float bb = (col < HID) ? ab2[col] : 0.f;
        float wv = (col < HID) ? aW3[col] : 0.f;
#pragma unroll
        for (int r = 0; r < 4; r++) {
            float v = fmaxf(acc2[c][r] + bb, 0.f);
            p[r] = fmaf(v, wv, p[r]);
        }
    }
#pragma unroll
    for (int off = 1; off < 16; off <<= 1)
#pragma unroll
        for (int r = 0; r < 4; r++) p[r] += __shfl_xor(p[r], off);
    if (m15 == 0)
#pragma unroll
        for (int r = 0; r < 4; r++) red[w][(l >> 4) * 4 + r] = p[r];
    __syncthreads();
    if (threadIdx.x < 32) {
        int ml = threadIdx.x;
        scores[blockIdx.x * 32 + ml] =
            red[(ml >> 4) * 2 + 0][ml & 15] + red[(ml >> 4) * 2 + 1][ml & 15] + ab3[0];
    }
}

// ---------------- k_spanfinal: 1279 blocks x 32 spans.
// phase0: softmax weights per span; phase1: h1 tile -> LDS frags; phase2: GEMM + dot(sW3) -> out
__global__ __launch_bounds__(256) void k_spanfinal(
    const float* __restrict__ scores, const float* __restrict__ Abuf,
    const float* __restrict__ Bbuf, const float* __restrict__ Ebuf,
    const float* __restrict__ wc,
    const unsigned short* __restrict__ fW2h, const unsigned short* __restrict__ fW2l,
    const float* __restrict__ sb2, const float* __restrict__ sW3,
    const float* __restrict__ sb3, float* __restrict__ out)
{
    __shared__ alignas(16) unsigned short hh[5120];
    __shared__ alignas(16) unsigned short hl[5120];
    __shared__ float wg[32][10];
    __shared__ int   stI[32], nnI[32];
    __shared__ float red[4][16];

    const int tid = threadIdx.x;
    const int s0  = blockIdx.x * 32;

    // phase 0: per-span softmax weights
    if (tid < 32) {
        int span = s0 + tid;
        int n = 1, start = 0;
        if (span < NSPAN) {
            int base = 0;
#pragma unroll
            for (int i = 1; i <= MAXW; i++) {
                int ww = T_TOK - i + 1;
                if (span < base + ww) { n = i; break; }
                base += ww;
            }
            start = span - base;
        }
        float sc[MAXW]; float mx = -1e30f;
#pragma unroll
        for (int i = 0; i < MAXW; i++) {
            sc[i] = (i < n) ? scores[start + i] : -1e30f;
            mx = fmaxf(mx, sc[i]);
        }
        float ssum = 0.f;
#pragma unroll
        for (int i = 0; i < MAXW; i++) { sc[i] = __expf(sc[i] - mx); ssum += sc[i]; }
        float inv = 1.f / ssum;
#pragma unroll
        for (int i = 0; i < MAXW; i++) wg[tid][i] = (i < n) ? sc[i] * inv : 0.f;
        stI[tid] = start;
        nnI[tid] = n;
    }
    __syncthreads();

    // phase 1: 32 spans x 40 col-groups = 1280 tasks, 5 per thread
#pragma unroll
    for (int it = 0; it < 5; ++it) {
        int task = it * 256 + tid;
        int sl = task / 40;
        int q  = task - sl * 40;
        int start = stI[sl], n = nnI[sl];
        int d0 = q * 4;
        float v0 = 0.f, v1 = 0.f, v2 = 0.f, v3 = 0.f;
        if (d0 < HID) {
            int endr = start + n - 1;
            float4 a4 = *(const float4*)(Abuf + (size_t)start * HPAD + d0);
            float4 b4 = *(const float4*)(Bbuf + (size_t)endr * HPAD + d0);
            float4 w4 = *(const float4*)(wc + (n - 1) * HPAD + d0);
            v0 = a4.x + b4.x + w4.x; v1 = a4.y + b4.y + w4.y;
            v2 = a4.z + b4.z + w4.z; v3 = a4.w + b4.w + w4.w;
            for (int i = 0; i < n; i++) {
                float4 e4 = *(const float4*)(Ebuf + (size_t)(start + i) * HPAD + d0);
                float a = wg[sl][i];
                v0 = fmaf(a, e4.x, v0); v1 = fmaf(a, e4.y, v1);
                v2 = fmaf(a, e4.z, v2); v3 = fmaf(a, e4.w, v3);
            }
            v0 = fmaxf(v0, 0.f); v1 = fmaxf(v1, 0.f);
            v2 = fmaxf(v2, 0.f); v3 = fmaxf(v3, 0.f);
        }
        int mtl = sl >> 4, sm = sl & 15;
        int kt = q >> 3, gg = (q >> 1) & 3, e0 = (q & 1) * 4;
        int slot = ((mtl * 5 + kt) * 64 + gg * 16 + sm) * 8 + e0;
        unsigned short h0 = bf_rne(v0), h1_ = bf_rne(v1), h2_ = bf_rne(v2), h3_ = bf_rne(v3);
        ushort4 hv, lv;
        hv.x = h0; hv.y = h1_; hv.z = h2_; hv.w = h3_;
        lv.x = bf_rne(v0 - bf_tof(h0)); lv.y = bf_rne(v1 - bf_tof(h1_));
        lv.z = bf_rne(v2 - bf_tof(h2_)); lv.w = bf_rne(v3 - bf_tof(h3_));
        *(ushort4*)(hh + slot) = hv;
        *(ushort4*)(hl + slot) = lv;
    }
    __syncthreads();

    // phase 2: GEMM (K=160) vs fW2 + relu + dot(sW3) -> out
    const int w = tid >> 6, l = tid & 63;
    const int mtl = w >> 1, nh = w & 1;
    const int m15 = l & 15;
    const bf16x8* pHh = (const bf16x8*)hh;
    const bf16x8* pHl = (const bf16x8*)hl;
    const bf16x8* pBh = (const bf16x8*)fW2h;
    const bf16x8* pBl = (const bf16x8*)fW2l;
    f32x4 acc[5];
#pragma unroll
    for (int c = 0; c < 5; c++) acc[c] = (f32x4){0.f, 0.f, 0.f, 0.f};
#pragma unroll
    for (int kt = 0; kt < 5; ++kt) {
        bf16x8 ah = pHh[(mtl * 5 + kt) * 64 + l];
        bf16x8 al = pHl[(mtl * 5 + kt) * 64 + l];
#pragma unroll
        for (int c = 0; c < 5; c++) {
            int ct = nh * 5 + c;
            bf16x8 bh = pBh[(size_t)(kt * NT + ct) * 64 + l];
            bf16x8 bl = pBl[(size_t)(kt * NT + ct) * 64 + l];
            acc[c] = __builtin_amdgcn_mfma_f32_16x16x32_bf16(ah, bh, acc[c], 0, 0, 0);
            acc[c] = __builtin_amdgcn_mfma_f32_16x16x32_bf16(al, bh, acc[c], 0, 0, 0);
            acc[c] = __builtin_amdgcn_mfma_f32_16x16x32_bf16(ah, bl, acc[c], 0, 0, 0);
        }
    }
    float p[4] = {0.f, 0.f, 0.f, 0.f};
#pragma unroll
    for (int c = 0; c < 5; c++) {
        int col = (nh * 5 + c) * 16 + m15;
        float bb = (col < HID) ? sb2[col] : 0.f;
        float wv = (col < HID) ? sW3[col] : 0.f;
#pragma unroll
        for (int r = 0; r < 4; r++) {
            float v = fmaxf(acc[c][r] + bb, 0.f);
            p[r] = fmaf(v, wv, p[r]);
        }
    }
#pragma unroll
    for (int off = 1; off < 16; off <<= 1)
#pragma unroll
        for (int r = 0; r < 4; r++) p[r] += __shfl_xor(p[r], off);
    if (m15 == 0)
#pragma unroll
        for (int r = 0; r < 4; r++) red[w][(l >> 4) * 4 + r] = p[r];
    __syncthreads();
    if (tid < 32) {
        int row = s0 + tid;
        if (row < NSPAN)
            out[row] = red[(tid >> 4) * 2 + 0][tid & 15] +
                       red[(tid >> 4) * 2 + 1][tid & 15] + sb3[0];
    }
}

extern "C" void kernel_launch(void* const* d_in, const int* in_sizes, int n_in,
                              void* d_out, int out_size, void* d_ws, size_t ws_size,
                              hipStream_t stream) {
    const float* embeds = (const float*)d_in[0];
    const float* states = (const float*)d_in[1];
    const float* aW1 = (const float*)d_in[2];
    const float* ab1 = (const float*)d_in[3];
    const float* aW2 = (const float*)d_in[4];
    const float* ab2 = (const float*)d_in[5];
    const float* aW3 = (const float*)d_in[6];
    const float* ab3 = (const float*)d_in[7];
    const float* wt  = (const float*)d_in[8];
    const float* sW1 = (const float*)d_in[9];
    const float* sb1 = (const float*)d_in[10];
    const float* sW2 = (const float*)d_in[11];
    const float* sb2 = (const float*)d_in[12];
    const float* sW3 = (const float*)d_in[13];
    const float* sb3 = (const float*)d_in[14];
    float* out = (float*)d_out;

    char* W = (char*)d_ws;
    float* Abuf   = (float*)(W + 0);            // 4096*160*4 = 2621440
    float* Bbuf   = (float*)(W + 2621440);
    float* Ebuf   = (float*)(W + 5242880);
    float* scores = (float*)(W + 7864320);      // 16384
    float* wcbuf  = (float*)(W + 7880704);      // 6400
    unsigned short* Sh   = (unsigned short*)(W + 7887104);    // 4096*416*2 = 3407872
    unsigned short* Sl   = (unsigned short*)(W + 11294976);
    unsigned short* Eh   = (unsigned short*)(W + 14702848);   // 4096*320*2 = 2621440
    unsigned short* El   = (unsigned short*)(W + 17324288);
    unsigned short* fW1h = (unsigned short*)(W + 19945728);   // 416*160*2 = 133120
    unsigned short* fW1l = (unsigned short*)(W + 20078848);
    unsigned short* fA1h = (unsigned short*)(W + 20211968);
    unsigned short* fA1l = (unsigned short*)(W + 20345088);
    unsigned short* fB1h = (unsigned short*)(W + 20478208);
    unsigned short* fB1l = (unsigned short*)(W + 20611328);
    unsigned short* fE1h = (unsigned short*)(W + 20744448);   // 320*160*2 = 102400
    unsigned short* fE1l = (unsigned short*)(W + 20846848);
    unsigned short* fA2h = (unsigned short*)(W + 20949248);   // 160*160*2 = 51200
    unsigned short* fA2l = (unsigned short*)(W + 21000448);
    unsigned short* fW2h = (unsigned short*)(W + 21051648);
    unsigned short* fW2l = (unsigned short*)(W + 21102848);

    // all frag conversions + width constants (1630 blocks)
    k_prep<<<1630, 256, 0, stream>>>(states, embeds, aW1, sW1, aW2, sW2, wt, sb1,
        Sh, Sl, Eh, El, fW1h, fW1l, fA1h, fA1l, fB1h, fB1l, fE1h, fE1l,
        fA2h, fA2l, fW2h, fW2l, wcbuf);
    // projections + fully fused attention -> scores (512 blocks)
    k_proj<<<dim3(128, 4), 256, 0, stream>>>(Sh, Sl, Eh, El,
        fW1h, fW1l, fA1h, fA1l, fB1h, fB1l, fE1h, fE1l, fA2h, fA2l,
        ab1, ab2, aW3, ab3, Abuf, Bbuf, Ebuf, scores);
    // spans + final MLP -> out (1279 blocks)
    k_spanfinal<<<1279, 256, 0, stream>>>(scores, Abuf, Bbuf, Ebuf, wcbuf,
        fW2h, fW2l, sb2, sW3, sb3, out);
}

// Round 6
// 41.099 us; speedup vs baseline: 9.1513x; 1.5489x over previous
//
#include <hip/hip_runtime.h>
#include <hip/hip_bf16.h>

#define T_TOK 4096
#define HID   150
#define HPAD  160
#define NSPAN 40915
#define MAXW  10
#define NT    10             // 160/16 col tiles

typedef __attribute__((ext_vector_type(8))) _Float16 f16x8;
typedef __attribute__((ext_vector_type(4))) _Float16 f16x4;
typedef __attribute__((ext_vector_type(4))) float    f32x4;

// ---------------- k_prep: all fp16 frag conversions + width constants (1630 blocks)
// [0,832)    states -> A-frags (KT=13)
// [832,1472) embeds -> A-frags (KT=10)
// [1472,1620) 6 weight tensors -> B-frags (590 tile-blocks)
// [1620,1630) width constants
__global__ __launch_bounds__(256) void k_prep(
    const float* __restrict__ states, const float* __restrict__ embeds,
    const float* __restrict__ aW1, const float* __restrict__ sW1,
    const float* __restrict__ aW2, const float* __restrict__ sW2,
    const float* __restrict__ wt, const float* __restrict__ sb1,
    _Float16* __restrict__ Sf, _Float16* __restrict__ Ef,
    _Float16* __restrict__ fW1, _Float16* __restrict__ fA1,
    _Float16* __restrict__ fB1, _Float16* __restrict__ fE1,
    _Float16* __restrict__ fA2, _Float16* __restrict__ fW2,
    float* __restrict__ wc)
{
    const int b = blockIdx.x;
    const int w = threadIdx.x >> 6, l = threadIdx.x & 63;

    if (b < 1472) {
        const float* src; int lda, srcK, KT; _Float16* d; int tb;
        if (b < 832) { src = states; lda = 400; srcK = 400; KT = 13; d = Sf; tb = b * 4 + w; }
        else         { src = embeds; lda = 300; srcK = 300; KT = 10; d = Ef; tb = (b - 832) * 4 + w; }
        int mt = tb / KT;
        int m = mt * 16 + (l & 15);
        int kbase = (tb - mt * KT) * 32 + (l >> 4) * 8;
        const float* row = src + (size_t)m * lda;
        f16x8 hv;
#pragma unroll
        for (int e = 0; e < 8; e++) {
            int k = kbase + e;
            float f = (k < srcK) ? row[k] : 0.f;
            hv[e] = (_Float16)f;
        }
        *(f16x8*)(d + ((size_t)tb * 64 + l) * 8) = hv;
    } else if (b < 1620) {
        int tw = (b - 1472) * 4 + w;
        if (tw >= 590) return;
        const float* src; int srcK, off; _Float16* d;
        if      (tw < 130) { src = aW1;             srcK = 400; off = 0;   d = fW1; }
        else if (tw < 260) { src = sW1;             srcK = 400; off = 130; d = fA1; }
        else if (tw < 390) { src = sW1 + 400 * HID; srcK = 400; off = 260; d = fB1; }
        else if (tw < 490) { src = sW1 + 800 * HID; srcK = 300; off = 390; d = fE1; }
        else if (tw < 540) { src = aW2;             srcK = 150; off = 490; d = fA2; }
        else               { src = sW2;             srcK = 150; off = 540; d = fW2; }
        int tb = tw - off;
        int kt = tb / NT, nt = tb - kt * NT;
        int n = nt * 16 + (l & 15);
        int kbase = kt * 32 + (l >> 4) * 8;
        f16x8 hv;
#pragma unroll
        for (int e = 0; e < 8; e++) {
            int k = kbase + e;
            float f = (k < srcK && n < HID) ? src[(size_t)k * HID + n] : 0.f;
            hv[e] = (_Float16)f;
        }
        *(f16x8*)(d + ((size_t)tb * 64 + l) * 8) = hv;
    } else {
        int n = b - 1619;            // 1..10
        int c = threadIdx.x;
        if (c >= HPAD) return;
        float s = 0.f;
        if (c < HID) {
            const int dt[11] = {0, 1, 2, 3, 4, 4, 4, 4, 5, 5, 5};
            const float* ww = wt + dt[n] * 20;
            s = sb1[c];
#pragma unroll
            for (int j = 0; j < 20; j++) s = fmaf(ww[j], sW1[(1100 + j) * HID + c], s);
        }
        wc[(n - 1) * HPAD + c] = s;
    }
}

// ---------------- k_proj: grid (128, 4). Block tile 32 x 160, 4 waves.
// y=0: states @ aW1 -> relu -> LDS frags -> @ aW2 -> relu -> dot(aW3) -> scores
// y=1,2,3: states/embeds projections -> Abuf/Bbuf/Ebuf (fp16)
__global__ __launch_bounds__(256) void k_proj(
    const _Float16* __restrict__ Sf, const _Float16* __restrict__ Ef,
    const _Float16* __restrict__ fW1, const _Float16* __restrict__ fA1,
    const _Float16* __restrict__ fB1, const _Float16* __restrict__ fE1,
    const _Float16* __restrict__ fA2,
    const float* __restrict__ ab1, const float* __restrict__ ab2,
    const float* __restrict__ aW3, const float* __restrict__ ab3,
    _Float16* __restrict__ Abuf, _Float16* __restrict__ Bbuf,
    _Float16* __restrict__ Ebuf, float* __restrict__ scores)
{
    __shared__ alignas(16) _Float16 hh[5120];   // 2 mtiles x 5 kt x 64 x 8
    __shared__ float red[4][16];

    const _Float16 *Af_, *Bf_; int KT; _Float16* C = nullptr;
    switch (blockIdx.y) {
        case 0: Af_=Sf; Bf_=fW1; KT=13; break;
        case 1: Af_=Sf; Bf_=fA1; KT=13; C=Abuf; break;
        case 2: Af_=Sf; Bf_=fB1; KT=13; C=Bbuf; break;
        default:Af_=Ef; Bf_=fE1; KT=10; C=Ebuf; break;
    }
    const int w = threadIdx.x >> 6, l = threadIdx.x & 63;
    const int mtl = w >> 1;
    const int mt  = blockIdx.x * 2 + mtl;
    const int nh  = w & 1;
    const f16x8* pA = (const f16x8*)Af_;
    const f16x8* pB = (const f16x8*)Bf_;

    f32x4 acc[5];
#pragma unroll
    for (int c = 0; c < 5; c++) acc[c] = (f32x4){0.f, 0.f, 0.f, 0.f};

#pragma unroll 2
    for (int kt = 0; kt < KT; ++kt) {
        f16x8 a = pA[(size_t)(mt * KT + kt) * 64 + l];
#pragma unroll
        for (int c = 0; c < 5; c++) {
            f16x8 bv = pB[(size_t)(kt * NT + nh * 5 + c) * 64 + l];
            acc[c] = __builtin_amdgcn_mfma_f32_16x16x32_f16(a, bv, acc[c], 0, 0, 0);
        }
    }

    if (blockIdx.y != 0) {
        const int m0 = mt * 16;
#pragma unroll
        for (int c = 0; c < 5; c++) {
            int col = (nh * 5 + c) * 16 + (l & 15);
#pragma unroll
            for (int r = 0; r < 4; r++) {
                int row = m0 + (l >> 4) * 4 + r;
                C[(size_t)row * HPAD + col] = (_Float16)acc[c][r];
            }
        }
        return;
    }

    // ---- fused attention: relu(H1 + ab1) -> LDS frags
    const int m15 = l & 15;
#pragma unroll
    for (int c = 0; c < 5; c++) {
        int u   = nh * 5 + c;
        int col = u * 16 + m15;
        float bb = (col < HID) ? ab1[col] : 0.f;
        int kt = u >> 1;
        int g  = (u & 1) * 2 + (m15 >> 3);
        int e  = m15 & 7;
#pragma unroll
        for (int r = 0; r < 4; r++) {
            int rloc = (l >> 4) * 4 + r;
            float v = fmaxf(acc[c][r] + bb, 0.f);
            hh[((mtl * 5 + kt) * 64 + g * 16 + rloc) * 8 + e] = (_Float16)v;
        }
    }
    __syncthreads();

    // ---- layer2 GEMM (K=160) from LDS frags vs fA2, + relu + dot(aW3)
    const f16x8* pH = (const f16x8*)hh;
    const f16x8* pB2 = (const f16x8*)fA2;
    f32x4 acc2[5];
#pragma unroll
    for (int c = 0; c < 5; c++) acc2[c] = (f32x4){0.f, 0.f, 0.f, 0.f};
#pragma unroll
    for (int kt = 0; kt < 5; ++kt) {
        f16x8 a = pH[(mtl * 5 + kt) * 64 + l];
#pragma unroll
        for (int c = 0; c < 5; c++) {
            f16x8 bv = pB2[(size_t)(kt * NT + nh * 5 + c) * 64 + l];
            acc2[c] = __builtin_amdgcn_mfma_f32_16x16x32_f16(a, bv, acc2[c], 0, 0, 0);
        }
    }
    float p[4] = {0.f, 0.f, 0.f, 0.f};
#pragma unroll
    for (int c = 0; c < 5; c++) {
        int col = (nh * 5 + c) * 16 + m15;
        float bb = (col < HID) ? ab2[col] : 0.f;
        float wv = (col < HID) ? aW3[col] : 0.f;
#pragma unroll
        for (int r = 0; r < 4; r++) {
            float v = fmaxf(acc2[c][r] + bb, 0.f);
            p[r] = fmaf(v, wv, p[r]);
        }
    }
#pragma unroll
    for (int off = 1; off < 16; off <<= 1)
#pragma unroll
        for (int r = 0; r < 4; r++) p[r] += __shfl_xor(p[r], off);
    if (m15 == 0)
#pragma unroll
        for (int r = 0; r < 4; r++) red[w][(l >> 4) * 4 + r] = p[r];
    __syncthreads();
    if (threadIdx.x < 32) {
        int ml = threadIdx.x;
        scores[blockIdx.x * 32 + ml] =
            red[(ml >> 4) * 2 + 0][ml & 15] + red[(ml >> 4) * 2 + 1][ml & 15] + ab3[0];
    }
}

// ---------------- k_spanfinal: 1279 blocks x 32 spans.
// phase0: softmax weights; phase1: h1 tile -> LDS fp16 frags; phase2: GEMM + dot(sW3) -> out
__global__ __launch_bounds__(256) void k_spanfinal(
    const float* __restrict__ scores, const _Float16* __restrict__ Abuf,
    const _Float16* __restrict__ Bbuf, const _Float16* __restrict__ Ebuf,
    const float* __restrict__ wc,
    const _Float16* __restrict__ fW2,
    const float* __restrict__ sb2, const float* __restrict__ sW3,
    const float* __restrict__ sb3, float* __restrict__ out)
{
    __shared__ alignas(16) _Float16 hh[5120];
    __shared__ float wg[32][10];
    __shared__ int   stI[32], nnI[32];
    __shared__ float red[4][16];

    const int tid = threadIdx.x;
    const int s0  = blockIdx.x * 32;

    // phase 0: per-span softmax weights
    if (tid < 32) {
        int span = s0 + tid;
        int n = 1, start = 0;
        if (span < NSPAN) {
            int base = 0;
#pragma unroll
            for (int i = 1; i <= MAXW; i++) {
                int ww = T_TOK - i + 1;
                if (span < base + ww) { n = i; break; }
                base += ww;
            }
            start = span - base;
        }
        float sc[MAXW]; float mx = -1e30f;
#pragma unroll
        for (int i = 0; i < MAXW; i++) {
            sc[i] = (i < n) ? scores[start + i] : -1e30f;
            mx = fmaxf(mx, sc[i]);
        }
        float ssum = 0.f;
#pragma unroll
        for (int i = 0; i < MAXW; i++) { sc[i] = __expf(sc[i] - mx); ssum += sc[i]; }
        float inv = 1.f / ssum;
#pragma unroll
        for (int i = 0; i < MAXW; i++) wg[tid][i] = (i < n) ? sc[i] * inv : 0.f;
        stI[tid] = start;
        nnI[tid] = n;
    }
    __syncthreads();

    // phase 1: 32 spans x 40 col-groups = 1280 tasks, 5 per thread
#pragma unroll
    for (int it = 0; it < 5; ++it) {
        int task = it * 256 + tid;
        int sl = task / 40;
        int q  = task - sl * 40;
        int start = stI[sl], n = nnI[sl];
        int d0 = q * 4;
        float v0 = 0.f, v1 = 0.f, v2 = 0.f, v3 = 0.f;
        if (d0 < HID) {
            int endr = start + n - 1;
            f16x4 a4 = *(const f16x4*)(Abuf + (size_t)start * HPAD + d0);
            f16x4 b4 = *(const f16x4*)(Bbuf + (size_t)endr * HPAD + d0);
            float4 w4 = *(const float4*)(wc + (n - 1) * HPAD + d0);
            v0 = (float)a4[0] + (float)b4[0] + w4.x;
            v1 = (float)a4[1] + (float)b4[1] + w4.y;
            v2 = (float)a4[2] + (float)b4[2] + w4.z;
            v3 = (float)a4[3] + (float)b4[3] + w4.w;
            for (int i = 0; i < n; i++) {
                f16x4 e4 = *(const f16x4*)(Ebuf + (size_t)(start + i) * HPAD + d0);
                float a = wg[sl][i];
                v0 = fmaf(a, (float)e4[0], v0); v1 = fmaf(a, (float)e4[1], v1);
                v2 = fmaf(a, (float)e4[2], v2); v3 = fmaf(a, (float)e4[3], v3);
            }
            v0 = fmaxf(v0, 0.f); v1 = fmaxf(v1, 0.f);
            v2 = fmaxf(v2, 0.f); v3 = fmaxf(v3, 0.f);
        }
        int mtl = sl >> 4, sm = sl & 15;
        int kt = q >> 3, gg = (q >> 1) & 3, e0 = (q & 1) * 4;
        int slot = ((mtl * 5 + kt) * 64 + gg * 16 + sm) * 8 + e0;
        f16x4 hv;
        hv[0] = (_Float16)v0; hv[1] = (_Float16)v1;
        hv[2] = (_Float16)v2; hv[3] = (_Float16)v3;
        *(f16x4*)(hh + slot) = hv;
    }
    __syncthreads();

    // phase 2: GEMM (K=160) vs fW2 + relu + dot(sW3) -> out
    const int w = tid >> 6, l = tid & 63;
    const int mtl = w >> 1, nh = w & 1;
    const int m15 = l & 15;
    const f16x8* pH = (const f16x8*)hh;
    const f16x8* pB = (const f16x8*)fW2;
    f32x4 acc[5];
#pragma unroll
    for (int c = 0; c < 5; c++) acc[c] = (f32x4){0.f, 0.f, 0.f, 0.f};
#pragma unroll
    for (int kt = 0; kt < 5; ++kt) {
        f16x8 a = pH[(mtl * 5 + kt) * 64 + l];
#pragma unroll
        for (int c = 0; c < 5; c++) {
            f16x8 bv = pB[(size_t)(kt * NT + nh * 5 + c) * 64 + l];
            acc[c] = __builtin_amdgcn_mfma_f32_16x16x32_f16(a, bv, acc[c], 0, 0, 0);
        }
    }
    float p[4] = {0.f, 0.f, 0.f, 0.f};
#pragma unroll
    for (int c = 0; c < 5; c++) {
        int col = (nh * 5 + c) * 16 + m15;
        float bb = (col < HID) ? sb2[col] : 0.f;
        float wv = (col < HID) ? sW3[col] : 0.f;
#pragma unroll
        for (int r = 0; r < 4; r++) {
            float v = fmaxf(acc[c][r] + bb, 0.f);
            p[r] = fmaf(v, wv, p[r]);
        }
    }
#pragma unroll
    for (int off = 1; off < 16; off <<= 1)
#pragma unroll
        for (int r = 0; r < 4; r++) p[r] += __shfl_xor(p[r], off);
    if (m15 == 0)
#pragma unroll
        for (int r = 0; r < 4; r++) red[w][(l >> 4) * 4 + r] = p[r];
    __syncthreads();
    if (tid < 32) {
        int row = s0 + tid;
        if (row < NSPAN)
            out[row] = red[(tid >> 4) * 2 + 0][tid & 15] +
                       red[(tid >> 4) * 2 + 1][tid & 15] + sb3[0];
    }
}

extern "C" void kernel_launch(void* const* d_in, const int* in_sizes, int n_in,
                              void* d_out, int out_size, void* d_ws, size_t ws_size,
                              hipStream_t stream) {
    const float* embeds = (const float*)d_in[0];
    const float* states = (const float*)d_in[1];
    const float* aW1 = (const float*)d_in[2];
    const float* ab1 = (const float*)d_in[3];
    const float* aW2 = (const float*)d_in[4];
    const float* ab2 = (const float*)d_in[5];
    const float* aW3 = (const float*)d_in[6];
    const float* ab3 = (const float*)d_in[7];
    const float* wt  = (const float*)d_in[8];
    const float* sW1 = (const float*)d_in[9];
    const float* sb1 = (const float*)d_in[10];
    const float* sW2 = (const float*)d_in[11];
    const float* sb2 = (const float*)d_in[12];
    const float* sW3 = (const float*)d_in[13];
    const float* sb3 = (const float*)d_in[14];
    float* out = (float*)d_out;

    char* W = (char*)d_ws;
    _Float16* Abuf = (_Float16*)(W + 0);          // 4096*160*2 = 1310720
    _Float16* Bbuf = (_Float16*)(W + 1310720);
    _Float16* Ebuf = (_Float16*)(W + 2621440);
    float* scores  = (float*)(W + 3932160);       // 16384
    float* wcbuf   = (float*)(W + 3948544);       // 6400
    _Float16* Sf   = (_Float16*)(W + 3954944);    // 4096*416*2 = 3407872
    _Float16* Ef   = (_Float16*)(W + 7362816);    // 4096*320*2 = 2621440
    _Float16* fW1  = (_Float16*)(W + 9984256);    // 416*160*2 = 133120
    _Float16* fA1  = (_Float16*)(W + 10117376);
    _Float16* fB1  = (_Float16*)(W + 10250496);
    _Float16* fE1  = (_Float16*)(W + 10383616);   // 320*160*2 = 102400
    _Float16* fA2  = (_Float16*)(W + 10486016);   // 160*160*2 = 51200
    _Float16* fW2  = (_Float16*)(W + 10537216);

    // all frag conversions + width constants (1630 blocks)
    k_prep<<<1630, 256, 0, stream>>>(states, embeds, aW1, sW1, aW2, sW2, wt, sb1,
        Sf, Ef, fW1, fA1, fB1, fE1, fA2, fW2, wcbuf);
    // projections + fully fused attention -> scores (512 blocks)
    k_proj<<<dim3(128, 4), 256, 0, stream>>>(Sf, Ef, fW1, fA1, fB1, fE1, fA2,
        ab1, ab2, aW3, ab3, Abuf, Bbuf, Ebuf, scores);
    // spans + final MLP -> out (1279 blocks)
    k_spanfinal<<<1279, 256, 0, stream>>>(scores, Abuf, Bbuf, Ebuf, wcbuf,
        fW2, sb2, sW3, sb3, out);
}

// Round 7
// 39.492 us; speedup vs baseline: 9.5236x; 1.0407x over previous
//
#include <hip/hip_runtime.h>
#include <hip/hip_bf16.h>

#define T_TOK 4096
#define HID   150
#define HPAD  160
#define NSPAN 40915
#define MAXW  10
#define NT    10             // 160/16 col tiles

typedef __attribute__((ext_vector_type(8))) _Float16 f16x8;
typedef __attribute__((ext_vector_type(4))) _Float16 f16x4;
typedef __attribute__((ext_vector_type(4))) float    f32x4;

// ---------------- k_prep: weight frag conversions + width constants (158 blocks)
// [0,148)   6 weight tensors -> B-frags (590 tile-waves, 4 per block)
// [148,158) width constants
__global__ __launch_bounds__(256) void k_prep(
    const float* __restrict__ aW1, const float* __restrict__ sW1,
    const float* __restrict__ aW2, const float* __restrict__ sW2,
    const float* __restrict__ wt, const float* __restrict__ sb1,
    _Float16* __restrict__ fW1, _Float16* __restrict__ fA1,
    _Float16* __restrict__ fB1, _Float16* __restrict__ fE1,
    _Float16* __restrict__ fA2, _Float16* __restrict__ fW2,
    float* __restrict__ wc)
{
    const int b = blockIdx.x;
    const int w = threadIdx.x >> 6, l = threadIdx.x & 63;

    if (b < 148) {
        int tw = b * 4 + w;
        if (tw >= 590) return;
        const float* src; int srcK, off; _Float16* d;
        if      (tw < 130) { src = aW1;             srcK = 400; off = 0;   d = fW1; }
        else if (tw < 260) { src = sW1;             srcK = 400; off = 130; d = fA1; }
        else if (tw < 390) { src = sW1 + 400 * HID; srcK = 400; off = 260; d = fB1; }
        else if (tw < 490) { src = sW1 + 800 * HID; srcK = 300; off = 390; d = fE1; }
        else if (tw < 540) { src = aW2;             srcK = 150; off = 490; d = fA2; }
        else               { src = sW2;             srcK = 150; off = 540; d = fW2; }
        int tb = tw - off;
        int kt = tb / NT, nt = tb - kt * NT;
        int n = nt * 16 + (l & 15);
        int kbase = kt * 32 + (l >> 4) * 8;
        f16x8 hv;
#pragma unroll
        for (int e = 0; e < 8; e++) {
            int k = kbase + e;
            float f = (k < srcK && n < HID) ? src[(size_t)k * HID + n] : 0.f;
            hv[e] = (_Float16)f;
        }
        *(f16x8*)(d + ((size_t)tb * 64 + l) * 8) = hv;
    } else {
        int n = b - 147;             // 1..10
        int c = threadIdx.x;
        if (c >= HPAD) return;
        float s = 0.f;
        if (c < HID) {
            const int dt[11] = {0, 1, 2, 3, 4, 4, 4, 4, 5, 5, 5};
            const float* ww = wt + dt[n] * 20;
            s = sb1[c];
#pragma unroll
            for (int j = 0; j < 20; j++) s = fmaf(ww[j], sW1[(1100 + j) * HID + c], s);
        }
        wc[(n - 1) * HPAD + c] = s;
    }
}

// ---------------- k_proj: grid (128, 4). Block tile 32 x 160, 4 waves.
// A-fragments converted inline from fp32 activations (no staging buffers).
// y=0: states @ aW1 -> relu -> LDS frags -> @ aW2 -> relu -> dot(aW3) -> scores
// y=1,2,3: states/embeds projections -> Abuf/Bbuf/Ebuf (fp16)
__global__ __launch_bounds__(256) void k_proj(
    const float* __restrict__ states, const float* __restrict__ embeds,
    const _Float16* __restrict__ fW1, const _Float16* __restrict__ fA1,
    const _Float16* __restrict__ fB1, const _Float16* __restrict__ fE1,
    const _Float16* __restrict__ fA2,
    const float* __restrict__ ab1, const float* __restrict__ ab2,
    const float* __restrict__ aW3, const float* __restrict__ ab3,
    _Float16* __restrict__ Abuf, _Float16* __restrict__ Bbuf,
    _Float16* __restrict__ Ebuf, float* __restrict__ scores)
{
    __shared__ alignas(16) _Float16 hh[5120];   // 2 mtiles x 5 kt x 64 x 8
    __shared__ float red[4][16];

    const float* Asrc; int lda, srcK, KT; const _Float16* Bf; _Float16* C = nullptr;
    switch (blockIdx.y) {
        case 0: Asrc = states; lda = 400; srcK = 400; KT = 13; Bf = fW1; break;
        case 1: Asrc = states; lda = 400; srcK = 400; KT = 13; Bf = fA1; C = Abuf; break;
        case 2: Asrc = states; lda = 400; srcK = 400; KT = 13; Bf = fB1; C = Bbuf; break;
        default:Asrc = embeds; lda = 300; srcK = 300; KT = 10; Bf = fE1; C = Ebuf; break;
    }
    const int w = threadIdx.x >> 6, l = threadIdx.x & 63;
    const int mtl = w >> 1;
    const int mt  = blockIdx.x * 2 + mtl;
    const int nh  = w & 1;
    const int m15 = l & 15;
    const int koff = (l >> 4) * 8;
    const float* arow = Asrc + (size_t)(mt * 16 + m15) * lda;
    const f16x8* pB = (const f16x8*)Bf;

    f32x4 acc[5];
#pragma unroll
    for (int c = 0; c < 5; c++) acc[c] = (f32x4){0.f, 0.f, 0.f, 0.f};

#pragma unroll 2
    for (int kt = 0; kt < KT; ++kt) {
        const int kbase = kt * 32 + koff;
        f16x8 a;
        if (kbase + 8 <= srcK) {
            float4 v0 = *(const float4*)(arow + kbase);
            float4 v1 = *(const float4*)(arow + kbase + 4);
            a[0] = (_Float16)v0.x; a[1] = (_Float16)v0.y;
            a[2] = (_Float16)v0.z; a[3] = (_Float16)v0.w;
            a[4] = (_Float16)v1.x; a[5] = (_Float16)v1.y;
            a[6] = (_Float16)v1.z; a[7] = (_Float16)v1.w;
        } else {
#pragma unroll
            for (int e = 0; e < 8; e++)
                a[e] = (_Float16)((kbase + e < srcK) ? arow[kbase + e] : 0.f);
        }
#pragma unroll
        for (int c = 0; c < 5; c++) {
            f16x8 bv = pB[(size_t)(kt * NT + nh * 5 + c) * 64 + l];
            acc[c] = __builtin_amdgcn_mfma_f32_16x16x32_f16(a, bv, acc[c], 0, 0, 0);
        }
    }

    if (blockIdx.y != 0) {
        const int m0 = mt * 16;
#pragma unroll
        for (int c = 0; c < 5; c++) {
            int col = (nh * 5 + c) * 16 + m15;
#pragma unroll
            for (int r = 0; r < 4; r++) {
                int row = m0 + (l >> 4) * 4 + r;
                C[(size_t)row * HPAD + col] = (_Float16)acc[c][r];
            }
        }
        return;
    }

    // ---- fused attention: relu(H1 + ab1) -> LDS frags
#pragma unroll
    for (int c = 0; c < 5; c++) {
        int u   = nh * 5 + c;
        int col = u * 16 + m15;
        float bb = (col < HID) ? ab1[col] : 0.f;
        int kt = u >> 1;
        int g  = (u & 1) * 2 + (m15 >> 3);
        int e  = m15 & 7;
#pragma unroll
        for (int r = 0; r < 4; r++) {
            int rloc = (l >> 4) * 4 + r;
            float v = fmaxf(acc[c][r] + bb, 0.f);
            hh[((mtl * 5 + kt) * 64 + g * 16 + rloc) * 8 + e] = (_Float16)v;
        }
    }
    __syncthreads();

    // ---- layer2 GEMM (K=160) from LDS frags vs fA2, + relu + dot(aW3)
    const f16x8* pH = (const f16x8*)hh;
    const f16x8* pB2 = (const f16x8*)fA2;
    f32x4 acc2[5];
#pragma unroll
    for (int c = 0; c < 5; c++) acc2[c] = (f32x4){0.f, 0.f, 0.f, 0.f};
#pragma unroll
    for (int kt = 0; kt < 5; ++kt) {
        f16x8 a = pH[(mtl * 5 + kt) * 64 + l];
#pragma unroll
        for (int c = 0; c < 5; c++) {
            f16x8 bv = pB2[(size_t)(kt * NT + nh * 5 + c) * 64 + l];
            acc2[c] = __builtin_amdgcn_mfma_f32_16x16x32_f16(a, bv, acc2[c], 0, 0, 0);
        }
    }
    float p[4] = {0.f, 0.f, 0.f, 0.f};
#pragma unroll
    for (int c = 0; c < 5; c++) {
        int col = (nh * 5 + c) * 16 + m15;
        float bb = (col < HID) ? ab2[col] : 0.f;
        float wv = (col < HID) ? aW3[col] : 0.f;
#pragma unroll
        for (int r = 0; r < 4; r++) {
            float v = fmaxf(acc2[c][r] + bb, 0.f);
            p[r] = fmaf(v, wv, p[r]);
        }
    }
#pragma unroll
    for (int off = 1; off < 16; off <<= 1)
#pragma unroll
        for (int r = 0; r < 4; r++) p[r] += __shfl_xor(p[r], off);
    if (m15 == 0)
#pragma unroll
        for (int r = 0; r < 4; r++) red[w][(l >> 4) * 4 + r] = p[r];
    __syncthreads();
    if (threadIdx.x < 32) {
        int ml = threadIdx.x;
        scores[blockIdx.x * 32 + ml] =
            red[(ml >> 4) * 2 + 0][ml & 15] + red[(ml >> 4) * 2 + 1][ml & 15] + ab3[0];
    }
}

// ---------------- k_spanfinal: 1279 blocks x 32 spans.
// phase0: softmax weights; phase1: h1 tile -> LDS fp16 frags (f16x8); phase2: GEMM -> out
__global__ __launch_bounds__(256) void k_spanfinal(
    const float* __restrict__ scores, const _Float16* __restrict__ Abuf,
    const _Float16* __restrict__ Bbuf, const _Float16* __restrict__ Ebuf,
    const float* __restrict__ wc,
    const _Float16* __restrict__ fW2,
    const float* __restrict__ sb2, const float* __restrict__ sW3,
    const float* __restrict__ sb3, float* __restrict__ out)
{
    __shared__ alignas(16) _Float16 hh[5120];
    __shared__ float wg[32][10];
    __shared__ int   stI[32], nnI[32];
    __shared__ float red[4][16];

    const int tid = threadIdx.x;
    const int s0  = blockIdx.x * 32;

    // phase 0: per-span softmax weights
    if (tid < 32) {
        int span = s0 + tid;
        int n = 1, start = 0;
        if (span < NSPAN) {
            int base = 0;
#pragma unroll
            for (int i = 1; i <= MAXW; i++) {
                int ww = T_TOK - i + 1;
                if (span < base + ww) { n = i; break; }
                base += ww;
            }
            start = span - base;
        }
        float sc[MAXW]; float mx = -1e30f;
#pragma unroll
        for (int i = 0; i < MAXW; i++) {
            sc[i] = (i < n) ? scores[start + i] : -1e30f;
            mx = fmaxf(mx, sc[i]);
        }
        float ssum = 0.f;
#pragma unroll
        for (int i = 0; i < MAXW; i++) { sc[i] = __expf(sc[i] - mx); ssum += sc[i]; }
        float inv = 1.f / ssum;
#pragma unroll
        for (int i = 0; i < MAXW; i++) wg[tid][i] = (i < n) ? sc[i] * inv : 0.f;
        stI[tid] = start;
        nnI[tid] = n;
    }
    __syncthreads();

    // phase 1: 32 spans x 20 col-groups (8 elems) = 640 tasks, 3 iterations
#pragma unroll
    for (int it = 0; it < 3; ++it) {
        int task = it * 256 + tid;
        if (task >= 640) break;
        int sl = task / 20;
        int q  = task - sl * 20;
        int start = stI[sl], n = nnI[sl];
        int d0 = q * 8;
        f16x8 a8 = *(const f16x8*)(Abuf + (size_t)start * HPAD + d0);
        f16x8 b8 = *(const f16x8*)(Bbuf + (size_t)(start + n - 1) * HPAD + d0);
        const float* wr = wc + (n - 1) * HPAD + d0;
        float v[8];
#pragma unroll
        for (int e = 0; e < 8; e++) v[e] = (float)a8[e] + (float)b8[e] + wr[e];
        for (int i = 0; i < n; i++) {
            f16x8 e8 = *(const f16x8*)(Ebuf + (size_t)(start + i) * HPAD + d0);
            float aa = wg[sl][i];
#pragma unroll
            for (int e = 0; e < 8; e++) v[e] = fmaf(aa, (float)e8[e], v[e]);
        }
        f16x8 hv;
#pragma unroll
        for (int e = 0; e < 8; e++) hv[e] = (_Float16)fmaxf(v[e], 0.f);
        // frag slot: kt = d0>>5, g = (d0>>3)&3
        int mtl = sl >> 4, sm = sl & 15;
        int kt = q >> 2, gg = q & 3;
        *(f16x8*)(hh + ((mtl * 5 + kt) * 64 + gg * 16 + sm) * 8) = hv;
    }
    __syncthreads();

    // phase 2: GEMM (K=160) vs fW2 + relu + dot(sW3) -> out
    const int w = tid >> 6, l = tid & 63;
    const int mtl = w >> 1, nh = w & 1;
    const int m15 = l & 15;
    const f16x8* pH = (const f16x8*)hh;
    const f16x8* pB = (const f16x8*)fW2;
    f32x4 acc[5];
#pragma unroll
    for (int c = 0; c < 5; c++) acc[c] = (f32x4){0.f, 0.f, 0.f, 0.f};
#pragma unroll
    for (int kt = 0; kt < 5; ++kt) {
        f16x8 a = pH[(mtl * 5 + kt) * 64 + l];
#pragma unroll
        for (int c = 0; c < 5; c++) {
            f16x8 bv = pB[(size_t)(kt * NT + nh * 5 + c) * 64 + l];
            acc[c] = __builtin_amdgcn_mfma_f32_16x16x32_f16(a, bv, acc[c], 0, 0, 0);
        }
    }
    float p[4] = {0.f, 0.f, 0.f, 0.f};
#pragma unroll
    for (int c = 0; c < 5; c++) {
        int col = (nh * 5 + c) * 16 + m15;
        float bb = (col < HID) ? sb2[col] : 0.f;
        float wv = (col < HID) ? sW3[col] : 0.f;
#pragma unroll
        for (int r = 0; r < 4; r++) {
            float v = fmaxf(acc[c][r] + bb, 0.f);
            p[r] = fmaf(v, wv, p[r]);
        }
    }
#pragma unroll
    for (int off = 1; off < 16; off <<= 1)
#pragma unroll
        for (int r = 0; r < 4; r++) p[r] += __shfl_xor(p[r], off);
    if (m15 == 0)
#pragma unroll
        for (int r = 0; r < 4; r++) red[w][(l >> 4) * 4 + r] = p[r];
    __syncthreads();
    if (tid < 32) {
        int row = s0 + tid;
        if (row < NSPAN)
            out[row] = red[(tid >> 4) * 2 + 0][tid & 15] +
                       red[(tid >> 4) * 2 + 1][tid & 15] + sb3[0];
    }
}

extern "C" void kernel_launch(void* const* d_in, const int* in_sizes, int n_in,
                              void* d_out, int out_size, void* d_ws, size_t ws_size,
                              hipStream_t stream) {
    const float* embeds = (const float*)d_in[0];
    const float* states = (const float*)d_in[1];
    const float* aW1 = (const float*)d_in[2];
    const float* ab1 = (const float*)d_in[3];
    const float* aW2 = (const float*)d_in[4];
    const float* ab2 = (const float*)d_in[5];
    const float* aW3 = (const float*)d_in[6];
    const float* ab3 = (const float*)d_in[7];
    const float* wt  = (const float*)d_in[8];
    const float* sW1 = (const float*)d_in[9];
    const float* sb1 = (const float*)d_in[10];
    const float* sW2 = (const float*)d_in[11];
    const float* sb2 = (const float*)d_in[12];
    const float* sW3 = (const float*)d_in[13];
    const float* sb3 = (const float*)d_in[14];
    float* out = (float*)d_out;

    char* W = (char*)d_ws;
    _Float16* Abuf = (_Float16*)(W + 0);          // 4096*160*2 = 1310720
    _Float16* Bbuf = (_Float16*)(W + 1310720);
    _Float16* Ebuf = (_Float16*)(W + 2621440);
    float* scores  = (float*)(W + 3932160);       // 16384
    float* wcbuf   = (float*)(W + 3948544);       // 6400
    _Float16* fW1  = (_Float16*)(W + 3954944);    // 416*160*2 = 133120
    _Float16* fA1  = (_Float16*)(W + 4088064);
    _Float16* fB1  = (_Float16*)(W + 4221184);
    _Float16* fE1  = (_Float16*)(W + 4354304);    // 320*160*2 = 102400
    _Float16* fA2  = (_Float16*)(W + 4456704);    // 160*160*2 = 51200
    _Float16* fW2  = (_Float16*)(W + 4507904);

    // weight frags + width constants (158 blocks)
    k_prep<<<158, 256, 0, stream>>>(aW1, sW1, aW2, sW2, wt, sb1,
                                    fW1, fA1, fB1, fE1, fA2, fW2, wcbuf);
    // projections + fused attention -> scores (512 blocks)
    k_proj<<<dim3(128, 4), 256, 0, stream>>>(states, embeds,
        fW1, fA1, fB1, fE1, fA2, ab1, ab2, aW3, ab3, Abuf, Bbuf, Ebuf, scores);
    // spans + final MLP -> out (1279 blocks)
    k_spanfinal<<<1279, 256, 0, stream>>>(scores, Abuf, Bbuf, Ebuf, wcbuf,
        fW2, sb2, sW3, sb3, out);
}